// Round 1
// baseline (1326.056 us; speedup 1.0000x reference)
//
#include <hip/hip_runtime.h>

// AutoCorrelation attention (Autoformer) for B=16, L=2048, d=512, top_k=7.
// Pipeline: split-f16 QKV projections (MFMA) -> packed complex FFT cross-corr
// -> channel-summed spectra -> iFFT -> top-7 lag select + softmax -> delayed
// aggregation -> output projection.

typedef _Float16 f16;
typedef _Float16 f16x4 __attribute__((ext_vector_type(4)));
typedef float    f32x4 __attribute__((ext_vector_type(4)));

// ---------------- conversion: f32 -> f16 hi (+ optional lo residual) --------
__global__ __launch_bounds__(256) void split_f16(
    const float* __restrict__ x, f16* __restrict__ hi, f16* __restrict__ lo,
    int n4, int wlo)
{
    int i = blockIdx.x * 256 + threadIdx.x;
    if (i >= n4) return;
    float4 v = ((const float4*)x)[i];
    f16x4 h = { (f16)v.x, (f16)v.y, (f16)v.z, (f16)v.w };
    ((f16x4*)hi)[i] = h;
    if (wlo) {
        f16x4 l = { (f16)(v.x - (float)h.x), (f16)(v.y - (float)h.y),
                    (f16)(v.z - (float)h.z), (f16)(v.w - (float)h.w) };
        ((f16x4*)lo)[i] = l;
    }
}

// ---------------- NT GEMM: C[M,N] = sum_s A_s * B_s^T (+bias), f16 MFMA -----
// A: M x 512 (row-major, K contig), B: N x 512. 128x128 tile, BK=64, 4 waves.
template<int NSLICE, int F16OUT>
__global__ __launch_bounds__(256) void gemm_nt(
    const f16* __restrict__ A0, const f16* __restrict__ A1, const f16* __restrict__ A2,
    const f16* __restrict__ B0, const f16* __restrict__ B1, const f16* __restrict__ B2,
    void* __restrict__ Cout, int N,
    const float* __restrict__ bias_row, const float* __restrict__ bias_col)
{
    constexpr int Ks = 512;
    __shared__ f16 As[128 * 64];
    __shared__ f16 Bs[128 * 64];
    const int tid  = threadIdx.x;
    const int wave = tid >> 6, lane = tid & 63;
    const int m0 = blockIdx.y * 128, n0 = blockIdx.x * 128;

    f32x4 acc[4][4];
#pragma unroll
    for (int m = 0; m < 4; ++m)
#pragma unroll
        for (int n = 0; n < 4; ++n) acc[m][n] = (f32x4){0.f, 0.f, 0.f, 0.f};

    const int srow = lane >> 3;          // row within 8-row staging group
    const int scol = (lane & 7) * 8;     // k octet

    const f16* Aslice[3] = {A0, A1, A2};
    const f16* Bslice[3] = {B0, B1, B2};

    const int fr = lane & 15;
    const int kg = (lane >> 4) * 4;
    const int warow = (wave >> 1) * 64 + fr;   // A fragment row base
    const int wbrow = (wave & 1) * 64 + fr;    // B fragment row base

#pragma unroll
    for (int s = 0; s < NSLICE; ++s) {
        const f16* Ap = Aslice[s];
        const f16* Bp = Bslice[s];
#pragma unroll 1
        for (int kk = 0; kk < Ks / 64; ++kk) {
            const int k0 = kk * 64;
#pragma unroll
            for (int q = 0; q < 4; ++q) {
                const int r = wave * 32 + q * 8 + srow;
                const f16* ga = Ap + (size_t)(m0 + r) * Ks + k0 + scol;
                const f16* gb = Bp + (size_t)(n0 + r) * Ks + k0 + scol;
                f16* la = &As[(wave * 32 + q * 8) * 64];   // wave-uniform base
                f16* lb = &Bs[(wave * 32 + q * 8) * 64];
                __builtin_amdgcn_global_load_lds(
                    (const __attribute__((address_space(1))) void*)ga,
                    (__attribute__((address_space(3))) void*)la, 16, 0, 0);
                __builtin_amdgcn_global_load_lds(
                    (const __attribute__((address_space(1))) void*)gb,
                    (__attribute__((address_space(3))) void*)lb, 16, 0, 0);
            }
            __syncthreads();
#pragma unroll
            for (int k2 = 0; k2 < 4; ++k2) {
                const int kb = k2 * 16 + kg;
                f16x4 af[4], bf[4];
#pragma unroll
                for (int m = 0; m < 4; ++m) af[m] = *(const f16x4*)&As[(warow + m * 16) * 64 + kb];
#pragma unroll
                for (int n = 0; n < 4; ++n) bf[n] = *(const f16x4*)&Bs[(wbrow + n * 16) * 64 + kb];
#pragma unroll
                for (int m = 0; m < 4; ++m)
#pragma unroll
                    for (int n = 0; n < 4; ++n)
                        acc[m][n] = __builtin_amdgcn_mfma_f32_16x16x16f16(af[m], bf[n], acc[m][n], 0, 0, 0);
            }
            __syncthreads();
        }
    }
    // epilogue: C/D layout col=lane&15, row=(lane>>4)*4+j
    const int crow = m0 + (wave >> 1) * 64 + (lane >> 4) * 4;
    const int ccol = n0 + (wave & 1) * 64 + (lane & 15);
#pragma unroll
    for (int m = 0; m < 4; ++m)
#pragma unroll
        for (int n = 0; n < 4; ++n) {
            const int col = ccol + n * 16;
            const float bc = bias_col ? bias_col[col] : 0.f;
#pragma unroll
            for (int j = 0; j < 4; ++j) {
                const int row = crow + m * 16 + j;
                float v = acc[m][n][j] + bc + (bias_row ? bias_row[row] : 0.f);
                if (F16OUT) ((f16*)Cout)[(size_t)row * N + col] = (f16)v;
                else        ((float*)Cout)[(size_t)row * N + col] = v;
            }
        }
}

// ---------------- 2048-pt radix-2 DIF FFT in LDS (nat in -> bitrev out) -----
__device__ __forceinline__ void fft2048(float2* z, const float2* tw, int tid)
{
#pragma unroll 1
    for (int s = 0; s < 11; ++s) {
        const int m = 1024 >> s;
#pragma unroll 1
        for (int idx = tid; idx < 1024; idx += 256) {
            const int j  = idx & (m - 1);
            const int i0 = ((idx & ~(m - 1)) << 1) | j;
            const int i1 = i0 + m;
            float2 a = z[i0], b = z[i1];
            z[i0] = make_float2(a.x + b.x, a.y + b.y);
            float dx = a.x - b.x, dy = a.y - b.y;
            float2 w = tw[j << s];
            z[i1] = make_float2(dx * w.x - dy * w.y, dx * w.y + dy * w.x);
        }
        __syncthreads();
    }
}

// z = q + i*k packed FFT; accumulate S_c = Q*conj(K) over 16 channels/block.
__global__ __launch_bounds__(256) void fft_corr(
    const float* __restrict__ Qt, const float* __restrict__ Kt,
    float2* __restrict__ Spart)
{
    __shared__ float2 z[2048];
    __shared__ float2 sacc[2048];
    __shared__ float2 tw[1024];
    const int tid = threadIdx.x;
    const int grp = blockIdx.x;   // 0..31 channel group
    const int b   = blockIdx.y;   // 0..15 batch

    for (int j = tid; j < 1024; j += 256) {
        float sv, cv;
        sincospif(-(float)j * (1.0f / 1024.0f), &sv, &cv);  // e^{-2*pi*i*j/2048}
        tw[j] = make_float2(cv, sv);
    }
    for (int f = tid; f < 2048; f += 256) sacc[f] = make_float2(0.f, 0.f);
    __syncthreads();

    for (int ch = 0; ch < 16; ++ch) {
        const int c = grp * 16 + ch;
        const float4* qr = (const float4*)(Qt + ((size_t)c * 16 + b) * 2048);
        const float4* kr = (const float4*)(Kt + ((size_t)c * 16 + b) * 2048);
        for (int t = tid; t < 512; t += 256) {
            float4 qv = qr[t], kv = kr[t];
            z[t * 4 + 0] = make_float2(qv.x, kv.x);
            z[t * 4 + 1] = make_float2(qv.y, kv.y);
            z[t * 4 + 2] = make_float2(qv.z, kv.z);
            z[t * 4 + 3] = make_float2(qv.w, kv.w);
        }
        __syncthreads();
        fft2048(z, tw, tid);
        for (int f = tid; f < 2048; f += 256) {
            const int rf = __brev((unsigned)f) >> 21;
            const int rc = __brev((unsigned)((2048 - f) & 2047)) >> 21;
            float2 Zf = z[rf];
            float2 Zc = z[rc]; Zc.y = -Zc.y;                  // conj(Z[N-f])
            float qx = 0.5f * (Zf.x + Zc.x), qy = 0.5f * (Zf.y + Zc.y);
            float dx = Zf.x - Zc.x,          dy = Zf.y - Zc.y;
            float kx = 0.5f * dy,            ky = -0.5f * dx; // K = -i*D/2
            sacc[f].x += qx * kx + qy * ky;                   // Q*conj(K)
            sacc[f].y += qy * kx - qx * ky;
        }
        __syncthreads();
    }
    float2* out = Spart + ((size_t)b * 32 + grp) * 2048;
    for (int f = tid; f < 2048; f += 256) out[f] = sacc[f];
}

// sum partials (fixed order), inverse FFT via conj trick, write mean_value.
__global__ __launch_bounds__(256) void ifft_mean(
    const float2* __restrict__ Spart, float* __restrict__ mv)
{
    __shared__ float2 z[2048];
    __shared__ float2 tw[1024];
    const int tid = threadIdx.x;
    const int b   = blockIdx.x;
    for (int f = tid; f < 2048; f += 256) {
        float sx = 0.f, sy = 0.f;
        for (int g = 0; g < 32; ++g) {
            float2 p = Spart[((size_t)b * 32 + g) * 2048 + f];
            sx += p.x; sy += p.y;
        }
        z[f] = make_float2(sx, -sy);   // conj(S)
    }
    for (int j = tid; j < 1024; j += 256) {
        float sv, cv;
        sincospif(-(float)j * (1.0f / 1024.0f), &sv, &cv);
        tw[j] = make_float2(cv, sv);
    }
    __syncthreads();
    fft2048(z, tw, tid);
    const float scale = 1.0f / (2048.0f * 512.0f);  // irfft 1/N and channel mean
    for (int t = tid; t < 2048; t += 256) {
        const int rt = __brev((unsigned)t) >> 21;
        mv[(size_t)b * 2048 + t] = z[rt].x * scale;
    }
}

// top-7 lags of batch-mean corr + per-batch softmax weights. One block.
__global__ __launch_bounds__(256) void select_topk(
    const float* __restrict__ mv, int* __restrict__ sel, float* __restrict__ wsm)
{
    __shared__ float u[2048];
    __shared__ float rv[256];
    __shared__ int   ri[256];
    __shared__ int   ssel[7];
    const int tid = threadIdx.x;
    for (int t = tid; t < 2048; t += 256) {
        float s = 0.f;
        for (int b = 0; b < 16; ++b) s += mv[b * 2048 + t];
        u[t] = s;
    }
    __syncthreads();
    for (int k = 0; k < 7; ++k) {
        float best = -3.4e38f; int bi = 0x7fffffff;
        for (int t = tid; t < 2048; t += 256)
            if (u[t] > best) { best = u[t]; bi = t; }
        rv[tid] = best; ri[tid] = bi;
        __syncthreads();
        for (int off = 128; off > 0; off >>= 1) {
            if (tid < off) {
                if (rv[tid + off] > rv[tid] ||
                    (rv[tid + off] == rv[tid] && ri[tid + off] < ri[tid])) {
                    rv[tid] = rv[tid + off]; ri[tid] = ri[tid + off];
                }
            }
            __syncthreads();
        }
        if (tid == 0) { ssel[k] = ri[0]; sel[k] = ri[0]; u[ri[0]] = -3.4e38f; }
        __syncthreads();
    }
    if (tid < 16) {
        float vals[7], mx = -3.4e38f;
        for (int k = 0; k < 7; ++k) { vals[k] = mv[tid * 2048 + ssel[k]]; mx = fmaxf(mx, vals[k]); }
        float se = 0.f;
        for (int k = 0; k < 7; ++k) { vals[k] = expf(vals[k] - mx); se += vals[k]; }
        for (int k = 0; k < 7; ++k) wsm[tid * 7 + k] = vals[k] / se;
    }
}

// agg[b,l,c] = sum_k w[b,k] * V[b,(l+sel[k])%L,c]
__global__ __launch_bounds__(256) void aggregate(
    const f16* __restrict__ V, const int* __restrict__ sel,
    const float* __restrict__ wsm, f16* __restrict__ agg)
{
    __shared__ int   sidx[7];
    __shared__ float sw[7];
    const int bl = blockIdx.x;
    const int b = bl >> 11, l = bl & 2047;
    if (threadIdx.x < 7) { sidx[threadIdx.x] = sel[threadIdx.x]; sw[threadIdx.x] = wsm[b * 7 + threadIdx.x]; }
    __syncthreads();
    const int c = threadIdx.x;
    float a0 = 0.f, a1 = 0.f;
#pragma unroll
    for (int k = 0; k < 7; ++k) {
        const int lk = (l + sidx[k]) & 2047;
        const f16* row = V + ((size_t)b * 2048 + lk) * 512;
        a0 += sw[k] * (float)row[c];
        a1 += sw[k] * (float)row[c + 256];
    }
    f16* orow = agg + ((size_t)b * 2048 + l) * 512;
    orow[c]       = (f16)a0;
    orow[c + 256] = (f16)a1;
}

extern "C" void kernel_launch(void* const* d_in, const int* in_sizes, int n_in,
                              void* d_out, int out_size, void* d_ws, size_t ws_size,
                              hipStream_t stream)
{
    (void)in_sizes; (void)n_in; (void)out_size; (void)ws_size;
    const float* queries = (const float*)d_in[0];
    const float* keys    = (const float*)d_in[1];
    const float* values  = (const float*)d_in[2];
    const float* Wq = (const float*)d_in[3];
    const float* bq = (const float*)d_in[4];
    const float* Wk = (const float*)d_in[5];
    const float* bk = (const float*)d_in[6];
    const float* Wv = (const float*)d_in[7];
    const float* bv = (const float*)d_in[8];
    const float* Wo = (const float*)d_in[9];
    const float* bo = (const float*)d_in[10];

    char* p = (char*)d_ws;
    f16*    xh  = (f16*)p;    p += 33554432;   // X hi (f16), reused per projection
    f16*    xl  = (f16*)p;    p += 33554432;   // X lo; later reused as agg
    float*  Qt  = (float*)p;  p += 67108864;   // Q transposed (c, b, t) f32
    float*  Kt  = (float*)p;  p += 67108864;   // K transposed f32
    f16*    Vb  = (f16*)p;    p += 33554432;   // V (b, l, c) f16
    f16*    wqh = (f16*)p;    p += 524288;
    f16*    wql = (f16*)p;    p += 524288;
    f16*    wkh = (f16*)p;    p += 524288;
    f16*    wkl = (f16*)p;    p += 524288;
    f16*    wvh = (f16*)p;    p += 524288;
    f16*    woh = (f16*)p;    p += 524288;
    float2* Sp  = (float2*)p; p += 8388608;    // 16 x 32 x 2048 complex partials
    float*  mv  = (float*)p;  p += 131072;     // mean_value 16 x 2048
    int*    sel = (int*)p;    p += 256;        // top-7 lags
    float*  wsm = (float*)p;  p += 512;        // softmax weights 16 x 7
    f16*    agg = xl;                          // reuse (xl dead after K GEMM)

    // weight conversions (hi/lo for Wq,Wk; hi for Wv,Wo)
    split_f16<<<256, 256, 0, stream>>>(Wq, wqh, wql, 65536, 1);
    split_f16<<<256, 256, 0, stream>>>(Wk, wkh, wkl, 65536, 1);
    split_f16<<<256, 256, 0, stream>>>(Wv, wvh, wvh, 65536, 0);
    split_f16<<<256, 256, 0, stream>>>(Wo, woh, woh, 65536, 0);

    // Q^T = Wq * queries^T (split: hh + lh + hl), stored (c, b*2048+t), +bq
    split_f16<<<16384, 256, 0, stream>>>(queries, xh, xl, 4194304, 1);
    gemm_nt<3, 0><<<dim3(256, 4), 256, 0, stream>>>(wqh, wql, wqh, xh, xh, xl, Qt, 32768, bq, nullptr);
    // K^T
    split_f16<<<16384, 256, 0, stream>>>(keys, xh, xl, 4194304, 1);
    gemm_nt<3, 0><<<dim3(256, 4), 256, 0, stream>>>(wkh, wkl, wkh, xh, xh, xl, Kt, 32768, bk, nullptr);
    // V natural (b,l,c), f16 out, +bv
    split_f16<<<16384, 256, 0, stream>>>(values, xh, xh, 4194304, 0);
    gemm_nt<1, 1><<<dim3(4, 256), 256, 0, stream>>>(xh, nullptr, nullptr, wvh, nullptr, nullptr, Vb, 512, nullptr, bv);

    // correlation spectra -> mean_value -> selection -> aggregation
    fft_corr<<<dim3(32, 16), 256, 0, stream>>>(Qt, Kt, Sp);
    ifft_mean<<<16, 256, 0, stream>>>(Sp, mv);
    select_topk<<<1, 256, 0, stream>>>(mv, sel, wsm);
    aggregate<<<32768, 256, 0, stream>>>(Vb, sel, wsm, agg);

    // out = agg @ Wo^T + bo  -> d_out f32
    gemm_nt<1, 0><<<dim3(4, 256), 256, 0, stream>>>(agg, nullptr, nullptr, woh, nullptr, nullptr, (float*)d_out, 512, nullptr, bo);
}

// Round 2
// 641.993 us; speedup vs baseline: 2.0655x; 2.0655x over previous
//
#include <hip/hip_runtime.h>

// AutoCorrelation attention (Autoformer) for B=16, L=2048, d=512, top_k=7.
// Pipeline: split-f16 QKV projections (MFMA) -> packed complex FFT cross-corr
// -> channel-summed spectra -> iFFT -> top-7 lag select + softmax -> delayed
// aggregation -> output projection.
//
// R1: XOR-swizzled LDS (both-sides: pre-swizzled global source for
// global_load_lds linear dest + swizzled ds_read col) to kill the 16-way
// bank conflict (SQ_LDS_BANK_CONFLICT was 1.9e8/dispatch).

typedef _Float16 f16;
typedef _Float16 f16x4 __attribute__((ext_vector_type(4)));
typedef float    f32x4 __attribute__((ext_vector_type(4)));

// ---------------- conversion: f32 -> f16 hi (+ optional lo residual) --------
__global__ __launch_bounds__(256) void split_f16(
    const float* __restrict__ x, f16* __restrict__ hi, f16* __restrict__ lo,
    int n4, int wlo)
{
    int i = blockIdx.x * 256 + threadIdx.x;
    if (i >= n4) return;
    float4 v = ((const float4*)x)[i];
    f16x4 h = { (f16)v.x, (f16)v.y, (f16)v.z, (f16)v.w };
    ((f16x4*)hi)[i] = h;
    if (wlo) {
        f16x4 l = { (f16)(v.x - (float)h.x), (f16)(v.y - (float)h.y),
                    (f16)(v.z - (float)h.z), (f16)(v.w - (float)h.w) };
        ((f16x4*)lo)[i] = l;
    }
}

// ---------------- NT GEMM: C[M,N] = sum_s A_s * B_s^T (+bias), f16 MFMA -----
// A: M x 512 (row-major, K contig), B: N x 512. 128x128 tile, BK=64, 4 waves.
// LDS layout: linear [128][64] f16, but column-units (16B) XOR-swizzled by
// (row&7): LDS[r][u] holds global unit u^(r&7). Staging pre-swizzles the
// global source col; reads apply the same XOR. 2 lanes/bank -> conflict-free.
template<int NSLICE, int F16OUT>
__global__ __launch_bounds__(256) void gemm_nt(
    const f16* __restrict__ A0, const f16* __restrict__ A1, const f16* __restrict__ A2,
    const f16* __restrict__ B0, const f16* __restrict__ B1, const f16* __restrict__ B2,
    void* __restrict__ Cout, int N,
    const float* __restrict__ bias_row, const float* __restrict__ bias_col)
{
    constexpr int Ks = 512;
    __shared__ f16 As[128 * 64];
    __shared__ f16 Bs[128 * 64];
    const int tid  = threadIdx.x;
    const int wave = tid >> 6, lane = tid & 63;
    const int m0 = blockIdx.y * 128, n0 = blockIdx.x * 128;

    f32x4 acc[4][4];
#pragma unroll
    for (int m = 0; m < 4; ++m)
#pragma unroll
        for (int n = 0; n < 4; ++n) acc[m][n] = (f32x4){0.f, 0.f, 0.f, 0.f};

    const int srow = lane >> 3;                          // row within 8-row staging group
    const int scol = (((lane & 7) ^ (srow & 7)) << 3);   // pre-swizzled global k octet

    const f16* Aslice[3] = {A0, A1, A2};
    const f16* Bslice[3] = {B0, B1, B2};

    const int fr = lane & 15;
    const int kg = (lane >> 4) * 4;
    const int rowm = fr & 7;                   // read-side swizzle key (const per lane)
    const int warow = (wave >> 1) * 64 + fr;   // A fragment row base
    const int wbrow = (wave & 1) * 64 + fr;    // B fragment row base

#pragma unroll
    for (int s = 0; s < NSLICE; ++s) {
        const f16* Ap = Aslice[s];
        const f16* Bp = Bslice[s];
#pragma unroll 1
        for (int kk = 0; kk < Ks / 64; ++kk) {
            const int k0 = kk * 64;
#pragma unroll
            for (int q = 0; q < 4; ++q) {
                const int r = wave * 32 + q * 8 + srow;
                const f16* ga = Ap + (size_t)(m0 + r) * Ks + k0 + scol;
                const f16* gb = Bp + (size_t)(n0 + r) * Ks + k0 + scol;
                f16* la = &As[(wave * 32 + q * 8) * 64];   // wave-uniform base
                f16* lb = &Bs[(wave * 32 + q * 8) * 64];
                __builtin_amdgcn_global_load_lds(
                    (const __attribute__((address_space(1))) void*)ga,
                    (__attribute__((address_space(3))) void*)la, 16, 0, 0);
                __builtin_amdgcn_global_load_lds(
                    (const __attribute__((address_space(1))) void*)gb,
                    (__attribute__((address_space(3))) void*)lb, 16, 0, 0);
            }
            __syncthreads();
#pragma unroll
            for (int k2 = 0; k2 < 4; ++k2) {
                const int kb = k2 * 16 + kg;
                const int col = (((kb >> 3) ^ rowm) << 3) | (kb & 7);  // swizzled read col
                f16x4 af[4], bf[4];
#pragma unroll
                for (int m = 0; m < 4; ++m) af[m] = *(const f16x4*)&As[(warow + m * 16) * 64 + col];
#pragma unroll
                for (int n = 0; n < 4; ++n) bf[n] = *(const f16x4*)&Bs[(wbrow + n * 16) * 64 + col];
#pragma unroll
                for (int m = 0; m < 4; ++m)
#pragma unroll
                    for (int n = 0; n < 4; ++n)
                        acc[m][n] = __builtin_amdgcn_mfma_f32_16x16x16f16(af[m], bf[n], acc[m][n], 0, 0, 0);
            }
            __syncthreads();
        }
    }
    // epilogue: C/D layout col=lane&15, row=(lane>>4)*4+j
    const int crow = m0 + (wave >> 1) * 64 + (lane >> 4) * 4;
    const int ccol = n0 + (wave & 1) * 64 + (lane & 15);
#pragma unroll
    for (int m = 0; m < 4; ++m)
#pragma unroll
        for (int n = 0; n < 4; ++n) {
            const int col = ccol + n * 16;
            const float bc = bias_col ? bias_col[col] : 0.f;
#pragma unroll
            for (int j = 0; j < 4; ++j) {
                const int row = crow + m * 16 + j;
                float v = acc[m][n][j] + bc + (bias_row ? bias_row[row] : 0.f);
                if (F16OUT) ((f16*)Cout)[(size_t)row * N + col] = (f16)v;
                else        ((float*)Cout)[(size_t)row * N + col] = v;
            }
        }
}

// ---------------- 2048-pt radix-2 DIF FFT in LDS (nat in -> bitrev out) -----
__device__ __forceinline__ void fft2048(float2* z, const float2* tw, int tid)
{
#pragma unroll 1
    for (int s = 0; s < 11; ++s) {
        const int m = 1024 >> s;
#pragma unroll 1
        for (int idx = tid; idx < 1024; idx += 256) {
            const int j  = idx & (m - 1);
            const int i0 = ((idx & ~(m - 1)) << 1) | j;
            const int i1 = i0 + m;
            float2 a = z[i0], b = z[i1];
            z[i0] = make_float2(a.x + b.x, a.y + b.y);
            float dx = a.x - b.x, dy = a.y - b.y;
            float2 w = tw[j << s];
            z[i1] = make_float2(dx * w.x - dy * w.y, dx * w.y + dy * w.x);
        }
        __syncthreads();
    }
}

// z = q + i*k packed FFT; accumulate S_c = Q*conj(K) over 16 channels/block.
__global__ __launch_bounds__(256) void fft_corr(
    const float* __restrict__ Qt, const float* __restrict__ Kt,
    float2* __restrict__ Spart)
{
    __shared__ float2 z[2048];
    __shared__ float2 sacc[2048];
    __shared__ float2 tw[1024];
    const int tid = threadIdx.x;
    const int grp = blockIdx.x;   // 0..31 channel group
    const int b   = blockIdx.y;   // 0..15 batch

    for (int j = tid; j < 1024; j += 256) {
        float sv, cv;
        sincospif(-(float)j * (1.0f / 1024.0f), &sv, &cv);  // e^{-2*pi*i*j/2048}
        tw[j] = make_float2(cv, sv);
    }
    for (int f = tid; f < 2048; f += 256) sacc[f] = make_float2(0.f, 0.f);
    __syncthreads();

    for (int ch = 0; ch < 16; ++ch) {
        const int c = grp * 16 + ch;
        const float4* qr = (const float4*)(Qt + ((size_t)c * 16 + b) * 2048);
        const float4* kr = (const float4*)(Kt + ((size_t)c * 16 + b) * 2048);
        for (int t = tid; t < 512; t += 256) {
            float4 qv = qr[t], kv = kr[t];
            z[t * 4 + 0] = make_float2(qv.x, kv.x);
            z[t * 4 + 1] = make_float2(qv.y, kv.y);
            z[t * 4 + 2] = make_float2(qv.z, kv.z);
            z[t * 4 + 3] = make_float2(qv.w, kv.w);
        }
        __syncthreads();
        fft2048(z, tw, tid);
        for (int f = tid; f < 2048; f += 256) {
            const int rf = __brev((unsigned)f) >> 21;
            const int rc = __brev((unsigned)((2048 - f) & 2047)) >> 21;
            float2 Zf = z[rf];
            float2 Zc = z[rc]; Zc.y = -Zc.y;                  // conj(Z[N-f])
            float qx = 0.5f * (Zf.x + Zc.x), qy = 0.5f * (Zf.y + Zc.y);
            float dx = Zf.x - Zc.x,          dy = Zf.y - Zc.y;
            float kx = 0.5f * dy,            ky = -0.5f * dx; // K = -i*D/2
            sacc[f].x += qx * kx + qy * ky;                   // Q*conj(K)
            sacc[f].y += qy * kx - qx * ky;
        }
        __syncthreads();
    }
    float2* out = Spart + ((size_t)b * 32 + grp) * 2048;
    for (int f = tid; f < 2048; f += 256) out[f] = sacc[f];
}

// sum partials (fixed order), inverse FFT via conj trick, write mean_value.
__global__ __launch_bounds__(256) void ifft_mean(
    const float2* __restrict__ Spart, float* __restrict__ mv)
{
    __shared__ float2 z[2048];
    __shared__ float2 tw[1024];
    const int tid = threadIdx.x;
    const int b   = blockIdx.x;
    for (int f = tid; f < 2048; f += 256) {
        float sx = 0.f, sy = 0.f;
        for (int g = 0; g < 32; ++g) {
            float2 p = Spart[((size_t)b * 32 + g) * 2048 + f];
            sx += p.x; sy += p.y;
        }
        z[f] = make_float2(sx, -sy);   // conj(S)
    }
    for (int j = tid; j < 1024; j += 256) {
        float sv, cv;
        sincospif(-(float)j * (1.0f / 1024.0f), &sv, &cv);
        tw[j] = make_float2(cv, sv);
    }
    __syncthreads();
    fft2048(z, tw, tid);
    const float scale = 1.0f / (2048.0f * 512.0f);  // irfft 1/N and channel mean
    for (int t = tid; t < 2048; t += 256) {
        const int rt = __brev((unsigned)t) >> 21;
        mv[(size_t)b * 2048 + t] = z[rt].x * scale;
    }
}

// top-7 lags of batch-mean corr + per-batch softmax weights. One block.
__global__ __launch_bounds__(256) void select_topk(
    const float* __restrict__ mv, int* __restrict__ sel, float* __restrict__ wsm)
{
    __shared__ float u[2048];
    __shared__ float rv[256];
    __shared__ int   ri[256];
    __shared__ int   ssel[7];
    const int tid = threadIdx.x;
    for (int t = tid; t < 2048; t += 256) {
        float s = 0.f;
        for (int b = 0; b < 16; ++b) s += mv[b * 2048 + t];
        u[t] = s;
    }
    __syncthreads();
    for (int k = 0; k < 7; ++k) {
        float best = -3.4e38f; int bi = 0x7fffffff;
        for (int t = tid; t < 2048; t += 256)
            if (u[t] > best) { best = u[t]; bi = t; }
        rv[tid] = best; ri[tid] = bi;
        __syncthreads();
        for (int off = 128; off > 0; off >>= 1) {
            if (tid < off) {
                if (rv[tid + off] > rv[tid] ||
                    (rv[tid + off] == rv[tid] && ri[tid + off] < ri[tid])) {
                    rv[tid] = rv[tid + off]; ri[tid] = ri[tid + off];
                }
            }
            __syncthreads();
        }
        if (tid == 0) { ssel[k] = ri[0]; sel[k] = ri[0]; u[ri[0]] = -3.4e38f; }
        __syncthreads();
    }
    if (tid < 16) {
        float vals[7], mx = -3.4e38f;
        for (int k = 0; k < 7; ++k) { vals[k] = mv[tid * 2048 + ssel[k]]; mx = fmaxf(mx, vals[k]); }
        float se = 0.f;
        for (int k = 0; k < 7; ++k) { vals[k] = expf(vals[k] - mx); se += vals[k]; }
        for (int k = 0; k < 7; ++k) wsm[tid * 7 + k] = vals[k] / se;
    }
}

// agg[b,l,c] = sum_k w[b,k] * V[b,(l+sel[k])%L,c]
__global__ __launch_bounds__(256) void aggregate(
    const f16* __restrict__ V, const int* __restrict__ sel,
    const float* __restrict__ wsm, f16* __restrict__ agg)
{
    __shared__ int   sidx[7];
    __shared__ float sw[7];
    const int bl = blockIdx.x;
    const int b = bl >> 11, l = bl & 2047;
    if (threadIdx.x < 7) { sidx[threadIdx.x] = sel[threadIdx.x]; sw[threadIdx.x] = wsm[b * 7 + threadIdx.x]; }
    __syncthreads();
    const int c = threadIdx.x;
    float a0 = 0.f, a1 = 0.f;
#pragma unroll
    for (int k = 0; k < 7; ++k) {
        const int lk = (l + sidx[k]) & 2047;
        const f16* row = V + ((size_t)b * 2048 + lk) * 512;
        a0 += sw[k] * (float)row[c];
        a1 += sw[k] * (float)row[c + 256];
    }
    f16* orow = agg + ((size_t)b * 2048 + l) * 512;
    orow[c]       = (f16)a0;
    orow[c + 256] = (f16)a1;
}

extern "C" void kernel_launch(void* const* d_in, const int* in_sizes, int n_in,
                              void* d_out, int out_size, void* d_ws, size_t ws_size,
                              hipStream_t stream)
{
    (void)in_sizes; (void)n_in; (void)out_size; (void)ws_size;
    const float* queries = (const float*)d_in[0];
    const float* keys    = (const float*)d_in[1];
    const float* values  = (const float*)d_in[2];
    const float* Wq = (const float*)d_in[3];
    const float* bq = (const float*)d_in[4];
    const float* Wk = (const float*)d_in[5];
    const float* bk = (const float*)d_in[6];
    const float* Wv = (const float*)d_in[7];
    const float* bv = (const float*)d_in[8];
    const float* Wo = (const float*)d_in[9];
    const float* bo = (const float*)d_in[10];

    char* p = (char*)d_ws;
    f16*    xh  = (f16*)p;    p += 33554432;   // X hi (f16), reused per projection
    f16*    xl  = (f16*)p;    p += 33554432;   // X lo; later reused as agg
    float*  Qt  = (float*)p;  p += 67108864;   // Q transposed (c, b, t) f32
    float*  Kt  = (float*)p;  p += 67108864;   // K transposed f32
    f16*    Vb  = (f16*)p;    p += 33554432;   // V (b, l, c) f16
    f16*    wqh = (f16*)p;    p += 524288;
    f16*    wql = (f16*)p;    p += 524288;
    f16*    wkh = (f16*)p;    p += 524288;
    f16*    wkl = (f16*)p;    p += 524288;
    f16*    wvh = (f16*)p;    p += 524288;
    f16*    woh = (f16*)p;    p += 524288;
    float2* Sp  = (float2*)p; p += 8388608;    // 16 x 32 x 2048 complex partials
    float*  mv  = (float*)p;  p += 131072;     // mean_value 16 x 2048
    int*    sel = (int*)p;    p += 256;        // top-7 lags
    float*  wsm = (float*)p;  p += 512;        // softmax weights 16 x 7
    f16*    agg = xl;                          // reuse (xl dead after K GEMM)

    // weight conversions (hi/lo for Wq,Wk; hi for Wv,Wo)
    split_f16<<<256, 256, 0, stream>>>(Wq, wqh, wql, 65536, 1);
    split_f16<<<256, 256, 0, stream>>>(Wk, wkh, wkl, 65536, 1);
    split_f16<<<256, 256, 0, stream>>>(Wv, wvh, wvh, 65536, 0);
    split_f16<<<256, 256, 0, stream>>>(Wo, woh, woh, 65536, 0);

    // Q^T = Wq * queries^T (split: hh + lh + hl), stored (c, b*2048+t), +bq
    split_f16<<<16384, 256, 0, stream>>>(queries, xh, xl, 4194304, 1);
    gemm_nt<3, 0><<<dim3(256, 4), 256, 0, stream>>>(wqh, wql, wqh, xh, xh, xl, Qt, 32768, bq, nullptr);
    // K^T
    split_f16<<<16384, 256, 0, stream>>>(keys, xh, xl, 4194304, 1);
    gemm_nt<3, 0><<<dim3(256, 4), 256, 0, stream>>>(wkh, wkl, wkh, xh, xh, xl, Kt, 32768, bk, nullptr);
    // V natural (b,l,c), f16 out, +bv
    split_f16<<<16384, 256, 0, stream>>>(values, xh, xh, 4194304, 0);
    gemm_nt<1, 1><<<dim3(4, 256), 256, 0, stream>>>(xh, nullptr, nullptr, wvh, nullptr, nullptr, Vb, 512, nullptr, bv);

    // correlation spectra -> mean_value -> selection -> aggregation
    fft_corr<<<dim3(32, 16), 256, 0, stream>>>(Qt, Kt, Sp);
    ifft_mean<<<16, 256, 0, stream>>>(Sp, mv);
    select_topk<<<1, 256, 0, stream>>>(mv, sel, wsm);
    aggregate<<<32768, 256, 0, stream>>>(Vb, sel, wsm, agg);

    // out = agg @ Wo^T + bo  -> d_out f32
    gemm_nt<1, 0><<<dim3(4, 256), 256, 0, stream>>>(agg, nullptr, nullptr, woh, nullptr, nullptr, (float*)d_out, 512, nullptr, bo);
}

// Round 3
// 512.200 us; speedup vs baseline: 2.5889x; 1.2534x over previous
//
#include <hip/hip_runtime.h>

// AutoCorrelation attention (Autoformer) for B=16, L=2048, d=512, top_k=7.
// R1: XOR-swizzled GEMM LDS (conflict-free MFMA staging).
// R2: FFT rewrite — fused double radix-2 LDS passes + register tail with
// direct bitrev->natural scatter, pad-8 z / pad-16 tw anti-conflict maps,
// register accumulation of the Hermitian half of S = sum_c Q conj(K).

typedef _Float16 f16;
typedef _Float16 f16x4 __attribute__((ext_vector_type(4)));
typedef float    f32x4 __attribute__((ext_vector_type(4)));

#define PSI(i) ((i) + ((i) >> 3))          // z anti-conflict pad (2048 -> 2304)
#define TWI(j) ((j) + ((j) >> 4))          // tw anti-conflict pad (1024 -> 1088)

__device__ __forceinline__ float2 f2add(float2 a, float2 b) { return make_float2(a.x + b.x, a.y + b.y); }
__device__ __forceinline__ float2 f2sub(float2 a, float2 b) { return make_float2(a.x - b.x, a.y - b.y); }
__device__ __forceinline__ float2 cmul(float2 a, float2 b)  { return make_float2(a.x * b.x - a.y * b.y, a.x * b.y + a.y * b.x); }

// ---------------- conversion: f32 -> f16 hi (+ optional lo residual) --------
__global__ __launch_bounds__(256) void split_f16(
    const float* __restrict__ x, f16* __restrict__ hi, f16* __restrict__ lo,
    int n4, int wlo)
{
    int i = blockIdx.x * 256 + threadIdx.x;
    if (i >= n4) return;
    float4 v = ((const float4*)x)[i];
    f16x4 h = { (f16)v.x, (f16)v.y, (f16)v.z, (f16)v.w };
    ((f16x4*)hi)[i] = h;
    if (wlo) {
        f16x4 l = { (f16)(v.x - (float)h.x), (f16)(v.y - (float)h.y),
                    (f16)(v.z - (float)h.z), (f16)(v.w - (float)h.w) };
        ((f16x4*)lo)[i] = l;
    }
}

// ---------------- NT GEMM: C[M,N] = sum_s A_s * B_s^T (+bias), f16 MFMA -----
template<int NSLICE, int F16OUT>
__global__ __launch_bounds__(256) void gemm_nt(
    const f16* __restrict__ A0, const f16* __restrict__ A1, const f16* __restrict__ A2,
    const f16* __restrict__ B0, const f16* __restrict__ B1, const f16* __restrict__ B2,
    void* __restrict__ Cout, int N,
    const float* __restrict__ bias_row, const float* __restrict__ bias_col)
{
    constexpr int Ks = 512;
    __shared__ f16 As[128 * 64];
    __shared__ f16 Bs[128 * 64];
    const int tid  = threadIdx.x;
    const int wave = tid >> 6, lane = tid & 63;
    const int m0 = blockIdx.y * 128, n0 = blockIdx.x * 128;

    f32x4 acc[4][4];
#pragma unroll
    for (int m = 0; m < 4; ++m)
#pragma unroll
        for (int n = 0; n < 4; ++n) acc[m][n] = (f32x4){0.f, 0.f, 0.f, 0.f};

    const int srow = lane >> 3;                          // row within 8-row staging group
    const int scol = (((lane & 7) ^ (srow & 7)) << 3);   // pre-swizzled global k octet

    const f16* Aslice[3] = {A0, A1, A2};
    const f16* Bslice[3] = {B0, B1, B2};

    const int fr = lane & 15;
    const int kg = (lane >> 4) * 4;
    const int rowm = fr & 7;                   // read-side swizzle key (const per lane)
    const int warow = (wave >> 1) * 64 + fr;   // A fragment row base
    const int wbrow = (wave & 1) * 64 + fr;    // B fragment row base

#pragma unroll
    for (int s = 0; s < NSLICE; ++s) {
        const f16* Ap = Aslice[s];
        const f16* Bp = Bslice[s];
#pragma unroll 1
        for (int kk = 0; kk < Ks / 64; ++kk) {
            const int k0 = kk * 64;
#pragma unroll
            for (int q = 0; q < 4; ++q) {
                const int r = wave * 32 + q * 8 + srow;
                const f16* ga = Ap + (size_t)(m0 + r) * Ks + k0 + scol;
                const f16* gb = Bp + (size_t)(n0 + r) * Ks + k0 + scol;
                f16* la = &As[(wave * 32 + q * 8) * 64];   // wave-uniform base
                f16* lb = &Bs[(wave * 32 + q * 8) * 64];
                __builtin_amdgcn_global_load_lds(
                    (const __attribute__((address_space(1))) void*)ga,
                    (__attribute__((address_space(3))) void*)la, 16, 0, 0);
                __builtin_amdgcn_global_load_lds(
                    (const __attribute__((address_space(1))) void*)gb,
                    (__attribute__((address_space(3))) void*)lb, 16, 0, 0);
            }
            __syncthreads();
#pragma unroll
            for (int k2 = 0; k2 < 4; ++k2) {
                const int kb = k2 * 16 + kg;
                const int col = (((kb >> 3) ^ rowm) << 3) | (kb & 7);  // swizzled read col
                f16x4 af[4], bf[4];
#pragma unroll
                for (int m = 0; m < 4; ++m) af[m] = *(const f16x4*)&As[(warow + m * 16) * 64 + col];
#pragma unroll
                for (int n = 0; n < 4; ++n) bf[n] = *(const f16x4*)&Bs[(wbrow + n * 16) * 64 + col];
#pragma unroll
                for (int m = 0; m < 4; ++m)
#pragma unroll
                    for (int n = 0; n < 4; ++n)
                        acc[m][n] = __builtin_amdgcn_mfma_f32_16x16x16f16(af[m], bf[n], acc[m][n], 0, 0, 0);
            }
            __syncthreads();
        }
    }
    const int crow = m0 + (wave >> 1) * 64 + (lane >> 4) * 4;
    const int ccol = n0 + (wave & 1) * 64 + (lane & 15);
#pragma unroll
    for (int m = 0; m < 4; ++m)
#pragma unroll
        for (int n = 0; n < 4; ++n) {
            const int col = ccol + n * 16;
            const float bc = bias_col ? bias_col[col] : 0.f;
#pragma unroll
            for (int j = 0; j < 4; ++j) {
                const int row = crow + m * 16 + j;
                float v = acc[m][n][j] + bc + (bias_row ? bias_row[row] : 0.f);
                if (F16OUT) ((f16*)Cout)[(size_t)row * N + col] = (f16)v;
                else        ((float*)Cout)[(size_t)row * N + col] = v;
            }
        }
}

// ---------------- 2048-pt FFT: fused double radix-2 DIF passes --------------
// z stored with PSI map; tw with TWI map. Natural-order in, passes cover
// stages m=1024..8; register tail does m=4,2,1 and scatters bitrev->natural.
template<int S>
__device__ __forceinline__ void fft_pass2(float2* __restrict__ z, const float2* __restrict__ tw, int tid)
{
    constexpr int m = 1024 >> S;
    constexpr int h = m >> 1;
#pragma unroll
    for (int rep = 0; rep < 2; ++rep) {
        const int idx = tid + rep * 256;
        const int j2  = idx & (h - 1);
        const int blk = idx >> (9 - S);
        const int i   = (blk << (11 - S)) + j2;
        const float2 w1 = tw[TWI(j2 << S)];
        const float2 w2 = tw[TWI(j2 << (S + 1))];
        float2 a = z[PSI(i)], b = z[PSI(i + h)], c = z[PSI(i + m)], d = z[PSI(i + m + h)];
        float2 a1 = f2add(a, c);
        float2 c1 = cmul(f2sub(a, c), w1);
        float2 b1 = f2add(b, d);
        float2 t0 = cmul(f2sub(b, d), w1);
        float2 d1 = make_float2(t0.y, -t0.x);            // * (-i)  (w_{j+h} = -i*w_j)
        z[PSI(i)]         = f2add(a1, b1);
        z[PSI(i + h)]     = cmul(f2sub(a1, b1), w2);
        z[PSI(i + m)]     = f2add(c1, d1);
        z[PSI(i + m + h)] = cmul(f2sub(c1, d1), w2);
    }
    __syncthreads();
}

__device__ __forceinline__ void fft_tail_scatter(float2* __restrict__ z, int tid)
{
    float2 v[8];
    const int p0 = tid * 8;
#pragma unroll
    for (int e = 0; e < 8; ++e) v[e] = z[PSI(p0 + e)];
    __syncthreads();
    // stage m=4: pairs (e, e+4), w = e^{-i pi e / 4}
    constexpr float RS = 0.70710678118654752f;
    const float2 W8[4] = { {1.f, 0.f}, {RS, -RS}, {0.f, -1.f}, {-RS, -RS} };
#pragma unroll
    for (int e = 0; e < 4; ++e) {
        float2 t = f2sub(v[e], v[e + 4]);
        v[e]     = f2add(v[e], v[e + 4]);
        v[e + 4] = cmul(t, W8[e]);
    }
    // stage m=2: pairs (b,b+2),(b+1,b+3) within 4-blocks; w(j=1) = -i
#pragma unroll
    for (int base = 0; base < 8; base += 4) {
        float2 t0 = f2sub(v[base], v[base + 2]);
        v[base]     = f2add(v[base], v[base + 2]);
        v[base + 2] = t0;
        float2 t1 = f2sub(v[base + 1], v[base + 3]);
        v[base + 1] = f2add(v[base + 1], v[base + 3]);
        v[base + 3] = make_float2(t1.y, -t1.x);
    }
    // stage m=1: pairs (e, e+1)
#pragma unroll
    for (int base = 0; base < 8; base += 2) {
        float2 t = f2sub(v[base], v[base + 1]);
        v[base]     = f2add(v[base], v[base + 1]);
        v[base + 1] = t;
    }
    // natural position p=8t+e holds Z[bitrev11(p)]; bitrev11(8t+e) = 256*br3(e) + br8(t)
    const int br8t = (int)(__brev((unsigned)tid) >> 24);
    const int BR3[8] = {0, 4, 2, 6, 1, 5, 3, 7};
#pragma unroll
    for (int e = 0; e < 8; ++e) {
        const int f = br8t + (BR3[e] << 8);
        z[PSI(f)] = v[e];
    }
    __syncthreads();
}

__device__ __forceinline__ void fft2048_natural(float2* __restrict__ z, const float2* __restrict__ tw, int tid)
{
    fft_pass2<0>(z, tw, tid);
    fft_pass2<2>(z, tw, tid);
    fft_pass2<4>(z, tw, tid);
    fft_pass2<6>(z, tw, tid);
    fft_tail_scatter(z, tid);   // z now holds Z[f] at natural f (PSI-mapped)
}

__device__ __forceinline__ void fill_tw(float2* __restrict__ tw, int tid)
{
    for (int j = tid; j < 1024; j += 256) {
        float sv, cv;
        sincospif(-(float)j * (1.0f / 1024.0f), &sv, &cv);   // e^{-2 pi i j / 2048}
        tw[TWI(j)] = make_float2(cv, sv);
    }
}

// 8 channels/block: z = q + i*k packed FFT; S_c = Q*conj(K) accumulated in
// registers over channels; Hermitian half f=0..1024 written to Sp.
__global__ __launch_bounds__(256) void fft_corr(
    const float* __restrict__ Qt, const float* __restrict__ Kt,
    float2* __restrict__ Sp)
{
    __shared__ float2 z[2304];
    __shared__ float2 tw[1088];
    const int tid = threadIdx.x;
    const int grp = blockIdx.x;   // 0..63 channel group (8 ch each)
    const int b   = blockIdx.y;   // 0..15 batch

    fill_tw(tw, tid);
    float2 racc[5];
#pragma unroll
    for (int r = 0; r < 5; ++r) racc[r] = make_float2(0.f, 0.f);
    __syncthreads();

    for (int ch = 0; ch < 8; ++ch) {
        const int c = grp * 8 + ch;
        const float4* qr = (const float4*)(Qt + ((size_t)c * 16 + b) * 2048);
        const float4* kr = (const float4*)(Kt + ((size_t)c * 16 + b) * 2048);
#pragma unroll
        for (int rep = 0; rep < 2; ++rep) {
            const int t4 = tid + rep * 256;
            float4 qv = qr[t4], kv = kr[t4];
            const int e0 = t4 * 4;
            z[PSI(e0 + 0)] = make_float2(qv.x, kv.x);
            z[PSI(e0 + 1)] = make_float2(qv.y, kv.y);
            z[PSI(e0 + 2)] = make_float2(qv.z, kv.z);
            z[PSI(e0 + 3)] = make_float2(qv.w, kv.w);
        }
        __syncthreads();
        fft2048_natural(z, tw, tid);
        // Hermitian unpack + product, natural-order coalesced reads
#pragma unroll
        for (int r = 0; r < 5; ++r) {
            const int f = tid + (r << 8);
            if (f <= 1024) {
                const int pf = (2048 - f) & 2047;
                float2 Zf  = z[PSI(f)];
                float2 Zc0 = z[PSI(pf)];                 // conj taken analytically below
                float qx = 0.5f * (Zf.x + Zc0.x), qy = 0.5f * (Zf.y - Zc0.y);
                float dx = Zf.x - Zc0.x,          dy = Zf.y + Zc0.y;
                float kx = 0.5f * dy,             ky = -0.5f * dx;   // K = -i*D/2
                racc[r].x += qx * kx + qy * ky;                      // Q*conj(K)
                racc[r].y += qy * kx - qx * ky;
            }
        }
        __syncthreads();
    }
    float2* out = Sp + ((size_t)b * 64 + grp) * 1025;
#pragma unroll
    for (int r = 0; r < 5; ++r) {
        const int f = tid + (r << 8);
        if (f <= 1024) out[f] = racc[r];
    }
}

// sum partials (fixed order), rebuild full spectrum from Hermitian half,
// inverse FFT via conj trick (same natural-order forward FFT), write mv.
__global__ __launch_bounds__(256) void ifft_mean(
    const float2* __restrict__ Sp, float* __restrict__ mv)
{
    __shared__ float2 z[2304];
    __shared__ float2 tw[1088];
    const int tid = threadIdx.x;
    const int b   = blockIdx.x;
    fill_tw(tw, tid);
#pragma unroll
    for (int r = 0; r < 5; ++r) {
        const int f = tid + (r << 8);
        if (f <= 1024) {
            float sx = 0.f, sy = 0.f;
            for (int g = 0; g < 64; ++g) {
                float2 p = Sp[((size_t)b * 64 + g) * 1025 + f];
                sx += p.x; sy += p.y;
            }
            z[PSI(f)] = make_float2(sx, -sy);                       // conj(S[f])
            if (f >= 1 && f <= 1023)
                z[PSI(2048 - f)] = make_float2(sx, sy);             // conj(S[2048-f]) = S[f]
        }
    }
    __syncthreads();
    fft2048_natural(z, tw, tid);
    const float scale = 1.0f / (2048.0f * 512.0f);  // irfft 1/N and channel mean
    for (int t = tid; t < 2048; t += 256)
        mv[(size_t)b * 2048 + t] = z[PSI(t)].x * scale;
}

// top-7 lags of batch-mean corr + per-batch softmax weights. One block.
__global__ __launch_bounds__(256) void select_topk(
    const float* __restrict__ mv, int* __restrict__ sel, float* __restrict__ wsm)
{
    __shared__ float u[2048];
    __shared__ float rv[256];
    __shared__ int   ri[256];
    __shared__ int   ssel[7];
    const int tid = threadIdx.x;
    for (int t = tid; t < 2048; t += 256) {
        float s = 0.f;
        for (int b = 0; b < 16; ++b) s += mv[b * 2048 + t];
        u[t] = s;
    }
    __syncthreads();
    for (int k = 0; k < 7; ++k) {
        float best = -3.4e38f; int bi = 0x7fffffff;
        for (int t = tid; t < 2048; t += 256)
            if (u[t] > best) { best = u[t]; bi = t; }
        rv[tid] = best; ri[tid] = bi;
        __syncthreads();
        for (int off = 128; off > 0; off >>= 1) {
            if (tid < off) {
                if (rv[tid + off] > rv[tid] ||
                    (rv[tid + off] == rv[tid] && ri[tid + off] < ri[tid])) {
                    rv[tid] = rv[tid + off]; ri[tid] = ri[tid + off];
                }
            }
            __syncthreads();
        }
        if (tid == 0) { ssel[k] = ri[0]; sel[k] = ri[0]; u[ri[0]] = -3.4e38f; }
        __syncthreads();
    }
    if (tid < 16) {
        float vals[7], mx = -3.4e38f;
        for (int k = 0; k < 7; ++k) { vals[k] = mv[tid * 2048 + ssel[k]]; mx = fmaxf(mx, vals[k]); }
        float se = 0.f;
        for (int k = 0; k < 7; ++k) { vals[k] = expf(vals[k] - mx); se += vals[k]; }
        for (int k = 0; k < 7; ++k) wsm[tid * 7 + k] = vals[k] / se;
    }
}

// agg[b,l,c] = sum_k w[b,k] * V[b,(l+sel[k])%L,c]
__global__ __launch_bounds__(256) void aggregate(
    const f16* __restrict__ V, const int* __restrict__ sel,
    const float* __restrict__ wsm, f16* __restrict__ agg)
{
    __shared__ int   sidx[7];
    __shared__ float sw[7];
    const int bl = blockIdx.x;
    const int b = bl >> 11, l = bl & 2047;
    if (threadIdx.x < 7) { sidx[threadIdx.x] = sel[threadIdx.x]; sw[threadIdx.x] = wsm[b * 7 + threadIdx.x]; }
    __syncthreads();
    const int c = threadIdx.x;
    float a0 = 0.f, a1 = 0.f;
#pragma unroll
    for (int k = 0; k < 7; ++k) {
        const int lk = (l + sidx[k]) & 2047;
        const f16* row = V + ((size_t)b * 2048 + lk) * 512;
        a0 += sw[k] * (float)row[c];
        a1 += sw[k] * (float)row[c + 256];
    }
    f16* orow = agg + ((size_t)b * 2048 + l) * 512;
    orow[c]       = (f16)a0;
    orow[c + 256] = (f16)a1;
}

extern "C" void kernel_launch(void* const* d_in, const int* in_sizes, int n_in,
                              void* d_out, int out_size, void* d_ws, size_t ws_size,
                              hipStream_t stream)
{
    (void)in_sizes; (void)n_in; (void)out_size; (void)ws_size;
    const float* queries = (const float*)d_in[0];
    const float* keys    = (const float*)d_in[1];
    const float* values  = (const float*)d_in[2];
    const float* Wq = (const float*)d_in[3];
    const float* bq = (const float*)d_in[4];
    const float* Wk = (const float*)d_in[5];
    const float* bk = (const float*)d_in[6];
    const float* Wv = (const float*)d_in[7];
    const float* bv = (const float*)d_in[8];
    const float* Wo = (const float*)d_in[9];
    const float* bo = (const float*)d_in[10];

    char* p = (char*)d_ws;
    f16*    xh  = (f16*)p;    p += 33554432;   // X hi (f16), reused per projection
    f16*    xl  = (f16*)p;    p += 33554432;   // X lo; later Sp, then agg
    float*  Qt  = (float*)p;  p += 67108864;   // Q transposed (c, b, t) f32
    float*  Kt  = (float*)p;  p += 67108864;   // K transposed f32
    f16*    Vb  = (f16*)p;    p += 33554432;   // V (b, l, c) f16
    f16*    wqh = (f16*)p;    p += 524288;
    f16*    wql = (f16*)p;    p += 524288;
    f16*    wkh = (f16*)p;    p += 524288;
    f16*    wkl = (f16*)p;    p += 524288;
    f16*    wvh = (f16*)p;    p += 524288;
    f16*    woh = (f16*)p;    p += 524288;
    p += 8388608;                              // (old Sp slot, unused)
    float*  mv  = (float*)p;  p += 131072;     // mean_value 16 x 2048
    int*    sel = (int*)p;    p += 256;        // top-7 lags
    float*  wsm = (float*)p;  p += 512;        // softmax weights 16 x 7
    float2* Sp  = (float2*)xl;                 // 16 x 64 x 1025 cplx, in dead xl
    f16*    agg = xl;                          // reuse after Sp consumed

    // weight conversions (hi/lo for Wq,Wk; hi for Wv,Wo)
    split_f16<<<256, 256, 0, stream>>>(Wq, wqh, wql, 65536, 1);
    split_f16<<<256, 256, 0, stream>>>(Wk, wkh, wkl, 65536, 1);
    split_f16<<<256, 256, 0, stream>>>(Wv, wvh, wvh, 65536, 0);
    split_f16<<<256, 256, 0, stream>>>(Wo, woh, woh, 65536, 0);

    // Q^T = Wq * queries^T (split: hh + lh + hl), stored (c, b*2048+t), +bq
    split_f16<<<16384, 256, 0, stream>>>(queries, xh, xl, 4194304, 1);
    gemm_nt<3, 0><<<dim3(256, 4), 256, 0, stream>>>(wqh, wql, wqh, xh, xh, xl, Qt, 32768, bq, nullptr);
    // K^T
    split_f16<<<16384, 256, 0, stream>>>(keys, xh, xl, 4194304, 1);
    gemm_nt<3, 0><<<dim3(256, 4), 256, 0, stream>>>(wkh, wkl, wkh, xh, xh, xl, Kt, 32768, bk, nullptr);
    // V natural (b,l,c), f16 out, +bv
    split_f16<<<16384, 256, 0, stream>>>(values, xh, xh, 4194304, 0);
    gemm_nt<1, 1><<<dim3(4, 256), 256, 0, stream>>>(xh, nullptr, nullptr, wvh, nullptr, nullptr, Vb, 512, nullptr, bv);

    // correlation spectra -> mean_value -> selection -> aggregation
    fft_corr<<<dim3(64, 16), 256, 0, stream>>>(Qt, Kt, Sp);
    ifft_mean<<<16, 256, 0, stream>>>(Sp, mv);
    select_topk<<<1, 256, 0, stream>>>(mv, sel, wsm);
    aggregate<<<32768, 256, 0, stream>>>(Vb, sel, wsm, agg);

    // out = agg @ Wo^T + bo  -> d_out f32
    gemm_nt<1, 0><<<dim3(4, 256), 256, 0, stream>>>(agg, nullptr, nullptr, woh, nullptr, nullptr, (float*)d_out, 512, nullptr, bo);
}

// Round 4
// 451.267 us; speedup vs baseline: 2.9385x; 1.1350x over previous
//
#include <hip/hip_runtime.h>

// AutoCorrelation attention (Autoformer) for B=16, L=2048, d=512, top_k=7.
// R1: XOR-swizzled GEMM LDS (conflict-free MFMA staging).
// R2: FFT rewrite — fused double radix-2 LDS passes + register tail,
//     natural-order scatter, pad-8/pad-16 anti-conflict maps.
// R3: 16x16x32 f16 MFMA (2x K per instruction, b128 fragment reads) +
//     XCD-aware tile decode (same-panel blocks co-resident on one XCD L2).

typedef _Float16 f16;
typedef _Float16 f16x8 __attribute__((ext_vector_type(8)));
typedef _Float16 f16x4 __attribute__((ext_vector_type(4)));
typedef float    f32x4 __attribute__((ext_vector_type(4)));

#define PSI(i) ((i) + ((i) >> 3))          // z anti-conflict pad (2048 -> 2304)
#define TWI(j) ((j) + ((j) >> 4))          // tw anti-conflict pad (1024 -> 1088)

__device__ __forceinline__ float2 f2add(float2 a, float2 b) { return make_float2(a.x + b.x, a.y + b.y); }
__device__ __forceinline__ float2 f2sub(float2 a, float2 b) { return make_float2(a.x - b.x, a.y - b.y); }
__device__ __forceinline__ float2 cmul(float2 a, float2 b)  { return make_float2(a.x * b.x - a.y * b.y, a.x * b.y + a.y * b.x); }

// ---------------- conversion: f32 -> f16 hi (+ optional lo residual) --------
__global__ __launch_bounds__(256) void split_f16(
    const float* __restrict__ x, f16* __restrict__ hi, f16* __restrict__ lo,
    int n4, int wlo)
{
    int i = blockIdx.x * 256 + threadIdx.x;
    if (i >= n4) return;
    float4 v = ((const float4*)x)[i];
    f16x4 h = { (f16)v.x, (f16)v.y, (f16)v.z, (f16)v.w };
    ((f16x4*)hi)[i] = h;
    if (wlo) {
        f16x4 l = { (f16)(v.x - (float)h.x), (f16)(v.y - (float)h.y),
                    (f16)(v.z - (float)h.z), (f16)(v.w - (float)h.w) };
        ((f16x4*)lo)[i] = l;
    }
}

// ---------------- NT GEMM: C[M,N] = sum_s A_s * B_s^T (+bias), f16 MFMA -----
// 1-D grid; tile decode: SWZ=1 groups same-nt (B-panel) blocks on one XCD,
// SWZ=2 groups same-mt (A-panel) blocks, SWZ=0 plain. Bijective when
// gridDim.x == 2^(MT_L2+NT_L2) and (for SWZ) NT_L2>=3 / MT_L2>=3.
template<int NSLICE, int F16OUT, int MT_L2, int NT_L2, int SWZ>
__global__ __launch_bounds__(256) void gemm_nt(
    const f16* __restrict__ A0, const f16* __restrict__ A1, const f16* __restrict__ A2,
    const f16* __restrict__ B0, const f16* __restrict__ B1, const f16* __restrict__ B2,
    void* __restrict__ Cout, int N,
    const float* __restrict__ bias_row, const float* __restrict__ bias_col)
{
    constexpr int Ks = 512;
    __shared__ f16 As[128 * 64];
    __shared__ f16 Bs[128 * 64];
    const int tid  = threadIdx.x;
    const int wave = tid >> 6, lane = tid & 63;

    int mt, nt;
    if (SWZ == 1) {
        const int xcd = blockIdx.x & 7, slot = blockIdx.x >> 3;
        mt = slot & ((1 << MT_L2) - 1);
        nt = (xcd << (NT_L2 - 3)) | (slot >> MT_L2);
    } else if (SWZ == 2) {
        const int xcd = blockIdx.x & 7, slot = blockIdx.x >> 3;
        nt = slot & ((1 << NT_L2) - 1);
        mt = (xcd << (MT_L2 - 3)) | (slot >> NT_L2);
    } else {
        nt = blockIdx.x & ((1 << NT_L2) - 1);
        mt = blockIdx.x >> NT_L2;
    }
    const int m0 = mt * 128, n0 = nt * 128;

    f32x4 acc[4][4];
#pragma unroll
    for (int m = 0; m < 4; ++m)
#pragma unroll
        for (int n = 0; n < 4; ++n) acc[m][n] = (f32x4){0.f, 0.f, 0.f, 0.f};

    const int srow = lane >> 3;                          // row within 8-row staging group
    const int scol = (((lane & 7) ^ (srow & 7)) << 3);   // pre-swizzled global k octet

    const f16* Aslice[3] = {A0, A1, A2};
    const f16* Bslice[3] = {B0, B1, B2};

    const int fr = lane & 15;
    const int kg = (lane >> 4) * 8;            // k-group base within 32-wide K step
    const int rowm = fr & 7;                   // read-side swizzle key (const per lane)
    const int warow = (wave >> 1) * 64 + fr;   // A fragment row base
    const int wbrow = (wave & 1) * 64 + fr;    // B fragment row base

#pragma unroll
    for (int s = 0; s < NSLICE; ++s) {
        const f16* Ap = Aslice[s];
        const f16* Bp = Bslice[s];
#pragma unroll 1
        for (int kk = 0; kk < Ks / 64; ++kk) {
            const int k0 = kk * 64;
#pragma unroll
            for (int q = 0; q < 4; ++q) {
                const int r = wave * 32 + q * 8 + srow;
                const f16* ga = Ap + (size_t)(m0 + r) * Ks + k0 + scol;
                const f16* gb = Bp + (size_t)(n0 + r) * Ks + k0 + scol;
                f16* la = &As[(wave * 32 + q * 8) * 64];   // wave-uniform base
                f16* lb = &Bs[(wave * 32 + q * 8) * 64];
                __builtin_amdgcn_global_load_lds(
                    (const __attribute__((address_space(1))) void*)ga,
                    (__attribute__((address_space(3))) void*)la, 16, 0, 0);
                __builtin_amdgcn_global_load_lds(
                    (const __attribute__((address_space(1))) void*)gb,
                    (__attribute__((address_space(3))) void*)lb, 16, 0, 0);
            }
            __syncthreads();
#pragma unroll
            for (int k2 = 0; k2 < 2; ++k2) {
                const int kb = k2 * 32 + kg;
                const int col = ((kb >> 3) ^ rowm) << 3;   // swizzled read col (16B units)
                f16x8 af[4], bf[4];
#pragma unroll
                for (int m = 0; m < 4; ++m) af[m] = *(const f16x8*)&As[(warow + m * 16) * 64 + col];
#pragma unroll
                for (int n = 0; n < 4; ++n) bf[n] = *(const f16x8*)&Bs[(wbrow + n * 16) * 64 + col];
#pragma unroll
                for (int m = 0; m < 4; ++m)
#pragma unroll
                    for (int n = 0; n < 4; ++n)
                        acc[m][n] = __builtin_amdgcn_mfma_f32_16x16x32_f16(af[m], bf[n], acc[m][n], 0, 0, 0);
            }
            __syncthreads();
        }
    }
    const int crow = m0 + (wave >> 1) * 64 + (lane >> 4) * 4;
    const int ccol = n0 + (wave & 1) * 64 + (lane & 15);
#pragma unroll
    for (int m = 0; m < 4; ++m)
#pragma unroll
        for (int n = 0; n < 4; ++n) {
            const int col = ccol + n * 16;
            const float bc = bias_col ? bias_col[col] : 0.f;
#pragma unroll
            for (int j = 0; j < 4; ++j) {
                const int row = crow + m * 16 + j;
                float v = acc[m][n][j] + bc + (bias_row ? bias_row[row] : 0.f);
                if (F16OUT) ((f16*)Cout)[(size_t)row * N + col] = (f16)v;
                else        ((float*)Cout)[(size_t)row * N + col] = v;
            }
        }
}

// ---------------- 2048-pt FFT: fused double radix-2 DIF passes --------------
template<int S>
__device__ __forceinline__ void fft_pass2(float2* __restrict__ z, const float2* __restrict__ tw, int tid)
{
    constexpr int m = 1024 >> S;
    constexpr int h = m >> 1;
#pragma unroll
    for (int rep = 0; rep < 2; ++rep) {
        const int idx = tid + rep * 256;
        const int j2  = idx & (h - 1);
        const int blk = idx >> (9 - S);
        const int i   = (blk << (11 - S)) + j2;
        const float2 w1 = tw[TWI(j2 << S)];
        const float2 w2 = tw[TWI(j2 << (S + 1))];
        float2 a = z[PSI(i)], b = z[PSI(i + h)], c = z[PSI(i + m)], d = z[PSI(i + m + h)];
        float2 a1 = f2add(a, c);
        float2 c1 = cmul(f2sub(a, c), w1);
        float2 b1 = f2add(b, d);
        float2 t0 = cmul(f2sub(b, d), w1);
        float2 d1 = make_float2(t0.y, -t0.x);            // * (-i)  (w_{j+h} = -i*w_j)
        z[PSI(i)]         = f2add(a1, b1);
        z[PSI(i + h)]     = cmul(f2sub(a1, b1), w2);
        z[PSI(i + m)]     = f2add(c1, d1);
        z[PSI(i + m + h)] = cmul(f2sub(c1, d1), w2);
    }
    __syncthreads();
}

__device__ __forceinline__ void fft_tail_scatter(float2* __restrict__ z, int tid)
{
    float2 v[8];
    const int p0 = tid * 8;
#pragma unroll
    for (int e = 0; e < 8; ++e) v[e] = z[PSI(p0 + e)];
    __syncthreads();
    constexpr float RS = 0.70710678118654752f;
    const float2 W8[4] = { {1.f, 0.f}, {RS, -RS}, {0.f, -1.f}, {-RS, -RS} };
#pragma unroll
    for (int e = 0; e < 4; ++e) {
        float2 t = f2sub(v[e], v[e + 4]);
        v[e]     = f2add(v[e], v[e + 4]);
        v[e + 4] = cmul(t, W8[e]);
    }
#pragma unroll
    for (int base = 0; base < 8; base += 4) {
        float2 t0 = f2sub(v[base], v[base + 2]);
        v[base]     = f2add(v[base], v[base + 2]);
        v[base + 2] = t0;
        float2 t1 = f2sub(v[base + 1], v[base + 3]);
        v[base + 1] = f2add(v[base + 1], v[base + 3]);
        v[base + 3] = make_float2(t1.y, -t1.x);
    }
#pragma unroll
    for (int base = 0; base < 8; base += 2) {
        float2 t = f2sub(v[base], v[base + 1]);
        v[base]     = f2add(v[base], v[base + 1]);
        v[base + 1] = t;
    }
    const int br8t = (int)(__brev((unsigned)tid) >> 24);
    const int BR3[8] = {0, 4, 2, 6, 1, 5, 3, 7};
#pragma unroll
    for (int e = 0; e < 8; ++e) {
        const int f = br8t + (BR3[e] << 8);
        z[PSI(f)] = v[e];
    }
    __syncthreads();
}

__device__ __forceinline__ void fft2048_natural(float2* __restrict__ z, const float2* __restrict__ tw, int tid)
{
    fft_pass2<0>(z, tw, tid);
    fft_pass2<2>(z, tw, tid);
    fft_pass2<4>(z, tw, tid);
    fft_pass2<6>(z, tw, tid);
    fft_tail_scatter(z, tid);   // z now holds Z[f] at natural f (PSI-mapped)
}

__device__ __forceinline__ void fill_tw(float2* __restrict__ tw, int tid)
{
    for (int j = tid; j < 1024; j += 256) {
        float sv, cv;
        sincospif(-(float)j * (1.0f / 1024.0f), &sv, &cv);   // e^{-2 pi i j / 2048}
        tw[TWI(j)] = make_float2(cv, sv);
    }
}

// 8 channels/block: z = q + i*k packed FFT; S_c = Q*conj(K) accumulated in
// registers over channels; Hermitian half f=0..1024 written to Sp.
__global__ __launch_bounds__(256) void fft_corr(
    const float* __restrict__ Qt, const float* __restrict__ Kt,
    float2* __restrict__ Sp)
{
    __shared__ float2 z[2304];
    __shared__ float2 tw[1088];
    const int tid = threadIdx.x;
    const int grp = blockIdx.x;   // 0..63 channel group (8 ch each)
    const int b   = blockIdx.y;   // 0..15 batch

    fill_tw(tw, tid);
    float2 racc[5];
#pragma unroll
    for (int r = 0; r < 5; ++r) racc[r] = make_float2(0.f, 0.f);
    __syncthreads();

    for (int ch = 0; ch < 8; ++ch) {
        const int c = grp * 8 + ch;
        const float4* qr = (const float4*)(Qt + ((size_t)c * 16 + b) * 2048);
        const float4* kr = (const float4*)(Kt + ((size_t)c * 16 + b) * 2048);
#pragma unroll
        for (int rep = 0; rep < 2; ++rep) {
            const int t4 = tid + rep * 256;
            float4 qv = qr[t4], kv = kr[t4];
            const int e0 = t4 * 4;
            z[PSI(e0 + 0)] = make_float2(qv.x, kv.x);
            z[PSI(e0 + 1)] = make_float2(qv.y, kv.y);
            z[PSI(e0 + 2)] = make_float2(qv.z, kv.z);
            z[PSI(e0 + 3)] = make_float2(qv.w, kv.w);
        }
        __syncthreads();
        fft2048_natural(z, tw, tid);
#pragma unroll
        for (int r = 0; r < 5; ++r) {
            const int f = tid + (r << 8);
            if (f <= 1024) {
                const int pf = (2048 - f) & 2047;
                float2 Zf  = z[PSI(f)];
                float2 Zc0 = z[PSI(pf)];
                float qx = 0.5f * (Zf.x + Zc0.x), qy = 0.5f * (Zf.y - Zc0.y);
                float dx = Zf.x - Zc0.x,          dy = Zf.y + Zc0.y;
                float kx = 0.5f * dy,             ky = -0.5f * dx;   // K = -i*D/2
                racc[r].x += qx * kx + qy * ky;                      // Q*conj(K)
                racc[r].y += qy * kx - qx * ky;
            }
        }
        __syncthreads();
    }
    float2* out = Sp + ((size_t)b * 64 + grp) * 1025;
#pragma unroll
    for (int r = 0; r < 5; ++r) {
        const int f = tid + (r << 8);
        if (f <= 1024) out[f] = racc[r];
    }
}

// sum partials (fixed order), rebuild full spectrum from Hermitian half,
// inverse FFT via conj trick (same natural-order forward FFT), write mv.
__global__ __launch_bounds__(256) void ifft_mean(
    const float2* __restrict__ Sp, float* __restrict__ mv)
{
    __shared__ float2 z[2304];
    __shared__ float2 tw[1088];
    const int tid = threadIdx.x;
    const int b   = blockIdx.x;
    fill_tw(tw, tid);
#pragma unroll
    for (int r = 0; r < 5; ++r) {
        const int f = tid + (r << 8);
        if (f <= 1024) {
            float sx = 0.f, sy = 0.f;
            for (int g = 0; g < 64; ++g) {
                float2 p = Sp[((size_t)b * 64 + g) * 1025 + f];
                sx += p.x; sy += p.y;
            }
            z[PSI(f)] = make_float2(sx, -sy);                       // conj(S[f])
            if (f >= 1 && f <= 1023)
                z[PSI(2048 - f)] = make_float2(sx, sy);             // conj(S[2048-f]) = S[f]
        }
    }
    __syncthreads();
    fft2048_natural(z, tw, tid);
    const float scale = 1.0f / (2048.0f * 512.0f);  // irfft 1/N and channel mean
    for (int t = tid; t < 2048; t += 256)
        mv[(size_t)b * 2048 + t] = z[PSI(t)].x * scale;
}

// top-7 lags of batch-mean corr + per-batch softmax weights. One block.
__global__ __launch_bounds__(256) void select_topk(
    const float* __restrict__ mv, int* __restrict__ sel, float* __restrict__ wsm)
{
    __shared__ float u[2048];
    __shared__ float rv[256];
    __shared__ int   ri[256];
    __shared__ int   ssel[7];
    const int tid = threadIdx.x;
    for (int t = tid; t < 2048; t += 256) {
        float s = 0.f;
        for (int b = 0; b < 16; ++b) s += mv[b * 2048 + t];
        u[t] = s;
    }
    __syncthreads();
    for (int k = 0; k < 7; ++k) {
        float best = -3.4e38f; int bi = 0x7fffffff;
        for (int t = tid; t < 2048; t += 256)
            if (u[t] > best) { best = u[t]; bi = t; }
        rv[tid] = best; ri[tid] = bi;
        __syncthreads();
        for (int off = 128; off > 0; off >>= 1) {
            if (tid < off) {
                if (rv[tid + off] > rv[tid] ||
                    (rv[tid + off] == rv[tid] && ri[tid + off] < ri[tid])) {
                    rv[tid] = rv[tid + off]; ri[tid] = ri[tid + off];
                }
            }
            __syncthreads();
        }
        if (tid == 0) { ssel[k] = ri[0]; sel[k] = ri[0]; u[ri[0]] = -3.4e38f; }
        __syncthreads();
    }
    if (tid < 16) {
        float vals[7], mx = -3.4e38f;
        for (int k = 0; k < 7; ++k) { vals[k] = mv[tid * 2048 + ssel[k]]; mx = fmaxf(mx, vals[k]); }
        float se = 0.f;
        for (int k = 0; k < 7; ++k) { vals[k] = expf(vals[k] - mx); se += vals[k]; }
        for (int k = 0; k < 7; ++k) wsm[tid * 7 + k] = vals[k] / se;
    }
}

// agg[b,l,c] = sum_k w[b,k] * V[b,(l+sel[k])%L,c]
__global__ __launch_bounds__(256) void aggregate(
    const f16* __restrict__ V, const int* __restrict__ sel,
    const float* __restrict__ wsm, f16* __restrict__ agg)
{
    __shared__ int   sidx[7];
    __shared__ float sw[7];
    const int bl = blockIdx.x;
    const int b = bl >> 11, l = bl & 2047;
    if (threadIdx.x < 7) { sidx[threadIdx.x] = sel[threadIdx.x]; sw[threadIdx.x] = wsm[b * 7 + threadIdx.x]; }
    __syncthreads();
    const int c = threadIdx.x;
    float a0 = 0.f, a1 = 0.f;
#pragma unroll
    for (int k = 0; k < 7; ++k) {
        const int lk = (l + sidx[k]) & 2047;
        const f16* row = V + ((size_t)b * 2048 + lk) * 512;
        a0 += sw[k] * (float)row[c];
        a1 += sw[k] * (float)row[c + 256];
    }
    f16* orow = agg + ((size_t)b * 2048 + l) * 512;
    orow[c]       = (f16)a0;
    orow[c + 256] = (f16)a1;
}

extern "C" void kernel_launch(void* const* d_in, const int* in_sizes, int n_in,
                              void* d_out, int out_size, void* d_ws, size_t ws_size,
                              hipStream_t stream)
{
    (void)in_sizes; (void)n_in; (void)out_size; (void)ws_size;
    const float* queries = (const float*)d_in[0];
    const float* keys    = (const float*)d_in[1];
    const float* values  = (const float*)d_in[2];
    const float* Wq = (const float*)d_in[3];
    const float* bq = (const float*)d_in[4];
    const float* Wk = (const float*)d_in[5];
    const float* bk = (const float*)d_in[6];
    const float* Wv = (const float*)d_in[7];
    const float* bv = (const float*)d_in[8];
    const float* Wo = (const float*)d_in[9];
    const float* bo = (const float*)d_in[10];

    char* p = (char*)d_ws;
    f16*    xh  = (f16*)p;    p += 33554432;   // X hi (f16), reused per projection
    f16*    xl  = (f16*)p;    p += 33554432;   // X lo; later Sp, then agg
    float*  Qt  = (float*)p;  p += 67108864;   // Q transposed (c, b, t) f32
    float*  Kt  = (float*)p;  p += 67108864;   // K transposed f32
    f16*    Vb  = (f16*)p;    p += 33554432;   // V (b, l, c) f16
    f16*    wqh = (f16*)p;    p += 524288;
    f16*    wql = (f16*)p;    p += 524288;
    f16*    wkh = (f16*)p;    p += 524288;
    f16*    wkl = (f16*)p;    p += 524288;
    f16*    wvh = (f16*)p;    p += 524288;
    f16*    woh = (f16*)p;    p += 524288;
    p += 8388608;                              // (old Sp slot, unused)
    float*  mv  = (float*)p;  p += 131072;     // mean_value 16 x 2048
    int*    sel = (int*)p;    p += 256;        // top-7 lags
    float*  wsm = (float*)p;  p += 512;        // softmax weights 16 x 7
    float2* Sp  = (float2*)xl;                 // 16 x 64 x 1025 cplx, in dead xl
    f16*    agg = xl;                          // reuse after Sp consumed

    // weight conversions (hi/lo for Wq,Wk; hi for Wv,Wo)
    split_f16<<<256, 256, 0, stream>>>(Wq, wqh, wql, 65536, 1);
    split_f16<<<256, 256, 0, stream>>>(Wk, wkh, wkl, 65536, 1);
    split_f16<<<256, 256, 0, stream>>>(Wv, wvh, wvh, 65536, 0);
    split_f16<<<256, 256, 0, stream>>>(Wo, woh, woh, 65536, 0);

    // Q^T = Wq * queries^T (split: hh + lh + hl), stored (c, b*2048+t), +bq
    // M=512 (4 tiles), N=32768 (256 tiles); SWZ=1 groups the 4 M-tiles of a
    // B-panel on one XCD.
    split_f16<<<16384, 256, 0, stream>>>(queries, xh, xl, 4194304, 1);
    gemm_nt<3, 0, 2, 8, 1><<<1024, 256, 0, stream>>>(wqh, wql, wqh, xh, xh, xl, Qt, 32768, bq, nullptr);
    // K^T
    split_f16<<<16384, 256, 0, stream>>>(keys, xh, xl, 4194304, 1);
    gemm_nt<3, 0, 2, 8, 1><<<1024, 256, 0, stream>>>(wkh, wkl, wkh, xh, xh, xl, Kt, 32768, bk, nullptr);
    // V natural (b,l,c), f16 out, +bv. M=32768 (256 tiles), N=512 (4 tiles);
    // SWZ=2 groups the 4 N-tiles of an A-panel on one XCD.
    split_f16<<<16384, 256, 0, stream>>>(values, xh, xh, 4194304, 0);
    gemm_nt<1, 1, 8, 2, 2><<<1024, 256, 0, stream>>>(xh, nullptr, nullptr, wvh, nullptr, nullptr, Vb, 512, nullptr, bv);

    // correlation spectra -> mean_value -> selection -> aggregation
    fft_corr<<<dim3(64, 16), 256, 0, stream>>>(Qt, Kt, Sp);
    ifft_mean<<<16, 256, 0, stream>>>(Sp, mv);
    select_topk<<<1, 256, 0, stream>>>(mv, sel, wsm);
    aggregate<<<32768, 256, 0, stream>>>(Vb, sel, wsm, agg);

    // out = agg @ Wo^T + bo  -> d_out f32
    gemm_nt<1, 0, 8, 2, 2><<<1024, 256, 0, stream>>>(agg, nullptr, nullptr, woh, nullptr, nullptr, (float*)d_out, 512, nullptr, bo);
}

// Round 5
// 369.163 us; speedup vs baseline: 3.5921x; 1.2224x over previous
//
#include <hip/hip_runtime.h>

// AutoCorrelation attention (Autoformer) for B=16, L=2048, d=512, top_k=7.
// R1: XOR-swizzled GEMM LDS (conflict-free MFMA staging).
// R2: FFT rewrite — fused double radix-2 LDS passes + register tail,
//     natural-order scatter, pad-8/pad-16 anti-conflict maps.
// R3: 16x16x32 f16 MFMA + XCD-aware tile decode.
// R4: plain-f16 Q/K (split-f16 dropped: selection margin ~100x after the
//     1/sqrt(512) channel-mean averaging), Qt/Kt stored f16 (halves GEMM
//     write + fft_corr read).

typedef _Float16 f16;
typedef _Float16 f16x8 __attribute__((ext_vector_type(8)));
typedef _Float16 f16x4 __attribute__((ext_vector_type(4)));
typedef float    f32x4 __attribute__((ext_vector_type(4)));

#define PSI(i) ((i) + ((i) >> 3))          // z anti-conflict pad (2048 -> 2304)
#define TWI(j) ((j) + ((j) >> 4))          // tw anti-conflict pad (1024 -> 1088)

__device__ __forceinline__ float2 f2add(float2 a, float2 b) { return make_float2(a.x + b.x, a.y + b.y); }
__device__ __forceinline__ float2 f2sub(float2 a, float2 b) { return make_float2(a.x - b.x, a.y - b.y); }
__device__ __forceinline__ float2 cmul(float2 a, float2 b)  { return make_float2(a.x * b.x - a.y * b.y, a.x * b.y + a.y * b.x); }

// ---------------- conversion: f32 -> f16 ------------------------------------
__global__ __launch_bounds__(256) void cvt_f16(
    const float* __restrict__ x, f16* __restrict__ hi, int n4)
{
    int i = blockIdx.x * 256 + threadIdx.x;
    if (i >= n4) return;
    float4 v = ((const float4*)x)[i];
    f16x4 h = { (f16)v.x, (f16)v.y, (f16)v.z, (f16)v.w };
    ((f16x4*)hi)[i] = h;
}

// ---------------- NT GEMM: C[M,N] = A * B^T (+bias), f16 16x16x32 MFMA ------
// 1-D grid; tile decode: SWZ=1 groups same-nt (B-panel) blocks on one XCD,
// SWZ=2 groups same-mt (A-panel) blocks, SWZ=0 plain.
template<int F16OUT, int MT_L2, int NT_L2, int SWZ>
__global__ __launch_bounds__(256) void gemm_nt(
    const f16* __restrict__ A0, const f16* __restrict__ B0,
    void* __restrict__ Cout, int N,
    const float* __restrict__ bias_row, const float* __restrict__ bias_col)
{
    constexpr int Ks = 512;
    __shared__ f16 As[128 * 64];
    __shared__ f16 Bs[128 * 64];
    const int tid  = threadIdx.x;
    const int wave = tid >> 6, lane = tid & 63;

    int mt, nt;
    if (SWZ == 1) {
        const int xcd = blockIdx.x & 7, slot = blockIdx.x >> 3;
        mt = slot & ((1 << MT_L2) - 1);
        nt = (xcd << (NT_L2 - 3)) | (slot >> MT_L2);
    } else if (SWZ == 2) {
        const int xcd = blockIdx.x & 7, slot = blockIdx.x >> 3;
        nt = slot & ((1 << NT_L2) - 1);
        mt = (xcd << (MT_L2 - 3)) | (slot >> NT_L2);
    } else {
        nt = blockIdx.x & ((1 << NT_L2) - 1);
        mt = blockIdx.x >> NT_L2;
    }
    const int m0 = mt * 128, n0 = nt * 128;

    f32x4 acc[4][4];
#pragma unroll
    for (int m = 0; m < 4; ++m)
#pragma unroll
        for (int n = 0; n < 4; ++n) acc[m][n] = (f32x4){0.f, 0.f, 0.f, 0.f};

    const int srow = lane >> 3;                          // row within 8-row staging group
    const int scol = (((lane & 7) ^ (srow & 7)) << 3);   // pre-swizzled global k octet

    const int fr = lane & 15;
    const int kg = (lane >> 4) * 8;            // k-group base within 32-wide K step
    const int rowm = fr & 7;                   // read-side swizzle key (const per lane)
    const int warow = (wave >> 1) * 64 + fr;   // A fragment row base
    const int wbrow = (wave & 1) * 64 + fr;    // B fragment row base

#pragma unroll 1
    for (int kk = 0; kk < Ks / 64; ++kk) {
        const int k0 = kk * 64;
#pragma unroll
        for (int q = 0; q < 4; ++q) {
            const int r = wave * 32 + q * 8 + srow;
            const f16* ga = A0 + (size_t)(m0 + r) * Ks + k0 + scol;
            const f16* gb = B0 + (size_t)(n0 + r) * Ks + k0 + scol;
            f16* la = &As[(wave * 32 + q * 8) * 64];   // wave-uniform base
            f16* lb = &Bs[(wave * 32 + q * 8) * 64];
            __builtin_amdgcn_global_load_lds(
                (const __attribute__((address_space(1))) void*)ga,
                (__attribute__((address_space(3))) void*)la, 16, 0, 0);
            __builtin_amdgcn_global_load_lds(
                (const __attribute__((address_space(1))) void*)gb,
                (__attribute__((address_space(3))) void*)lb, 16, 0, 0);
        }
        __syncthreads();
#pragma unroll
        for (int k2 = 0; k2 < 2; ++k2) {
            const int kb = k2 * 32 + kg;
            const int col = ((kb >> 3) ^ rowm) << 3;   // swizzled read col (16B units)
            f16x8 af[4], bf[4];
#pragma unroll
            for (int m = 0; m < 4; ++m) af[m] = *(const f16x8*)&As[(warow + m * 16) * 64 + col];
#pragma unroll
            for (int n = 0; n < 4; ++n) bf[n] = *(const f16x8*)&Bs[(wbrow + n * 16) * 64 + col];
#pragma unroll
            for (int m = 0; m < 4; ++m)
#pragma unroll
                for (int n = 0; n < 4; ++n)
                    acc[m][n] = __builtin_amdgcn_mfma_f32_16x16x32_f16(af[m], bf[n], acc[m][n], 0, 0, 0);
        }
        __syncthreads();
    }
    const int crow = m0 + (wave >> 1) * 64 + (lane >> 4) * 4;
    const int ccol = n0 + (wave & 1) * 64 + (lane & 15);
#pragma unroll
    for (int m = 0; m < 4; ++m)
#pragma unroll
        for (int n = 0; n < 4; ++n) {
            const int col = ccol + n * 16;
            const float bc = bias_col ? bias_col[col] : 0.f;
#pragma unroll
            for (int j = 0; j < 4; ++j) {
                const int row = crow + m * 16 + j;
                float v = acc[m][n][j] + bc + (bias_row ? bias_row[row] : 0.f);
                if (F16OUT) ((f16*)Cout)[(size_t)row * N + col] = (f16)v;
                else        ((float*)Cout)[(size_t)row * N + col] = v;
            }
        }
}

// ---------------- 2048-pt FFT: fused double radix-2 DIF passes --------------
template<int S>
__device__ __forceinline__ void fft_pass2(float2* __restrict__ z, const float2* __restrict__ tw, int tid)
{
    constexpr int m = 1024 >> S;
    constexpr int h = m >> 1;
#pragma unroll
    for (int rep = 0; rep < 2; ++rep) {
        const int idx = tid + rep * 256;
        const int j2  = idx & (h - 1);
        const int blk = idx >> (9 - S);
        const int i   = (blk << (11 - S)) + j2;
        const float2 w1 = tw[TWI(j2 << S)];
        const float2 w2 = tw[TWI(j2 << (S + 1))];
        float2 a = z[PSI(i)], b = z[PSI(i + h)], c = z[PSI(i + m)], d = z[PSI(i + m + h)];
        float2 a1 = f2add(a, c);
        float2 c1 = cmul(f2sub(a, c), w1);
        float2 b1 = f2add(b, d);
        float2 t0 = cmul(f2sub(b, d), w1);
        float2 d1 = make_float2(t0.y, -t0.x);            // * (-i)  (w_{j+h} = -i*w_j)
        z[PSI(i)]         = f2add(a1, b1);
        z[PSI(i + h)]     = cmul(f2sub(a1, b1), w2);
        z[PSI(i + m)]     = f2add(c1, d1);
        z[PSI(i + m + h)] = cmul(f2sub(c1, d1), w2);
    }
    __syncthreads();
}

__device__ __forceinline__ void fft_tail_scatter(float2* __restrict__ z, int tid)
{
    float2 v[8];
    const int p0 = tid * 8;
#pragma unroll
    for (int e = 0; e < 8; ++e) v[e] = z[PSI(p0 + e)];
    __syncthreads();
    constexpr float RS = 0.70710678118654752f;
    const float2 W8[4] = { {1.f, 0.f}, {RS, -RS}, {0.f, -1.f}, {-RS, -RS} };
#pragma unroll
    for (int e = 0; e < 4; ++e) {
        float2 t = f2sub(v[e], v[e + 4]);
        v[e]     = f2add(v[e], v[e + 4]);
        v[e + 4] = cmul(t, W8[e]);
    }
#pragma unroll
    for (int base = 0; base < 8; base += 4) {
        float2 t0 = f2sub(v[base], v[base + 2]);
        v[base]     = f2add(v[base], v[base + 2]);
        v[base + 2] = t0;
        float2 t1 = f2sub(v[base + 1], v[base + 3]);
        v[base + 1] = f2add(v[base + 1], v[base + 3]);
        v[base + 3] = make_float2(t1.y, -t1.x);
    }
#pragma unroll
    for (int base = 0; base < 8; base += 2) {
        float2 t = f2sub(v[base], v[base + 1]);
        v[base]     = f2add(v[base], v[base + 1]);
        v[base + 1] = t;
    }
    const int br8t = (int)(__brev((unsigned)tid) >> 24);
    const int BR3[8] = {0, 4, 2, 6, 1, 5, 3, 7};
#pragma unroll
    for (int e = 0; e < 8; ++e) {
        const int f = br8t + (BR3[e] << 8);
        z[PSI(f)] = v[e];
    }
    __syncthreads();
}

__device__ __forceinline__ void fft2048_natural(float2* __restrict__ z, const float2* __restrict__ tw, int tid)
{
    fft_pass2<0>(z, tw, tid);
    fft_pass2<2>(z, tw, tid);
    fft_pass2<4>(z, tw, tid);
    fft_pass2<6>(z, tw, tid);
    fft_tail_scatter(z, tid);   // z now holds Z[f] at natural f (PSI-mapped)
}

__device__ __forceinline__ void fill_tw(float2* __restrict__ tw, int tid)
{
    for (int j = tid; j < 1024; j += 256) {
        float sv, cv;
        sincospif(-(float)j * (1.0f / 1024.0f), &sv, &cv);   // e^{-2 pi i j / 2048}
        tw[TWI(j)] = make_float2(cv, sv);
    }
}

// 8 channels/block: z = q + i*k packed FFT; S_c = Q*conj(K) accumulated in
// registers over channels; Hermitian half f=0..1024 written to Sp.
__global__ __launch_bounds__(256) void fft_corr(
    const f16* __restrict__ Qt, const f16* __restrict__ Kt,
    float2* __restrict__ Sp)
{
    __shared__ float2 z[2304];
    __shared__ float2 tw[1088];
    const int tid = threadIdx.x;
    const int grp = blockIdx.x;   // 0..63 channel group (8 ch each)
    const int b   = blockIdx.y;   // 0..15 batch

    fill_tw(tw, tid);
    float2 racc[5];
#pragma unroll
    for (int r = 0; r < 5; ++r) racc[r] = make_float2(0.f, 0.f);
    __syncthreads();

    for (int ch = 0; ch < 8; ++ch) {
        const int c = grp * 8 + ch;
        const f16x8* qr = (const f16x8*)(Qt + ((size_t)c * 16 + b) * 2048);
        const f16x8* kr = (const f16x8*)(Kt + ((size_t)c * 16 + b) * 2048);
        f16x8 qv = qr[tid], kv = kr[tid];
        const int e0 = tid * 8;
#pragma unroll
        for (int j = 0; j < 8; ++j)
            z[PSI(e0 + j)] = make_float2((float)qv[j], (float)kv[j]);
        __syncthreads();
        fft2048_natural(z, tw, tid);
#pragma unroll
        for (int r = 0; r < 5; ++r) {
            const int f = tid + (r << 8);
            if (f <= 1024) {
                const int pf = (2048 - f) & 2047;
                float2 Zf  = z[PSI(f)];
                float2 Zc0 = z[PSI(pf)];
                float qx = 0.5f * (Zf.x + Zc0.x), qy = 0.5f * (Zf.y - Zc0.y);
                float dx = Zf.x - Zc0.x,          dy = Zf.y + Zc0.y;
                float kx = 0.5f * dy,             ky = -0.5f * dx;   // K = -i*D/2
                racc[r].x += qx * kx + qy * ky;                      // Q*conj(K)
                racc[r].y += qy * kx - qx * ky;
            }
        }
        __syncthreads();
    }
    float2* out = Sp + ((size_t)b * 64 + grp) * 1025;
#pragma unroll
    for (int r = 0; r < 5; ++r) {
        const int f = tid + (r << 8);
        if (f <= 1024) out[f] = racc[r];
    }
}

// sum partials (fixed order), rebuild full spectrum from Hermitian half,
// inverse FFT via conj trick (same natural-order forward FFT), write mv.
__global__ __launch_bounds__(256) void ifft_mean(
    const float2* __restrict__ Sp, float* __restrict__ mv)
{
    __shared__ float2 z[2304];
    __shared__ float2 tw[1088];
    const int tid = threadIdx.x;
    const int b   = blockIdx.x;
    fill_tw(tw, tid);
#pragma unroll
    for (int r = 0; r < 5; ++r) {
        const int f = tid + (r << 8);
        if (f <= 1024) {
            float sx = 0.f, sy = 0.f;
            for (int g = 0; g < 64; ++g) {
                float2 p = Sp[((size_t)b * 64 + g) * 1025 + f];
                sx += p.x; sy += p.y;
            }
            z[PSI(f)] = make_float2(sx, -sy);                       // conj(S[f])
            if (f >= 1 && f <= 1023)
                z[PSI(2048 - f)] = make_float2(sx, sy);             // conj(S[2048-f]) = S[f]
        }
    }
    __syncthreads();
    fft2048_natural(z, tw, tid);
    const float scale = 1.0f / (2048.0f * 512.0f);  // irfft 1/N and channel mean
    for (int t = tid; t < 2048; t += 256)
        mv[(size_t)b * 2048 + t] = z[PSI(t)].x * scale;
}

// top-7 lags of batch-mean corr + per-batch softmax weights. One block.
__global__ __launch_bounds__(256) void select_topk(
    const float* __restrict__ mv, int* __restrict__ sel, float* __restrict__ wsm)
{
    __shared__ float u[2048];
    __shared__ float rv[256];
    __shared__ int   ri[256];
    __shared__ int   ssel[7];
    const int tid = threadIdx.x;
    for (int t = tid; t < 2048; t += 256) {
        float s = 0.f;
        for (int b = 0; b < 16; ++b) s += mv[b * 2048 + t];
        u[t] = s;
    }
    __syncthreads();
    for (int k = 0; k < 7; ++k) {
        float best = -3.4e38f; int bi = 0x7fffffff;
        for (int t = tid; t < 2048; t += 256)
            if (u[t] > best) { best = u[t]; bi = t; }
        rv[tid] = best; ri[tid] = bi;
        __syncthreads();
        for (int off = 128; off > 0; off >>= 1) {
            if (tid < off) {
                if (rv[tid + off] > rv[tid] ||
                    (rv[tid + off] == rv[tid] && ri[tid + off] < ri[tid])) {
                    rv[tid] = rv[tid + off]; ri[tid] = ri[tid + off];
                }
            }
            __syncthreads();
        }
        if (tid == 0) { ssel[k] = ri[0]; sel[k] = ri[0]; u[ri[0]] = -3.4e38f; }
        __syncthreads();
    }
    if (tid < 16) {
        float vals[7], mx = -3.4e38f;
        for (int k = 0; k < 7; ++k) { vals[k] = mv[tid * 2048 + ssel[k]]; mx = fmaxf(mx, vals[k]); }
        float se = 0.f;
        for (int k = 0; k < 7; ++k) { vals[k] = expf(vals[k] - mx); se += vals[k]; }
        for (int k = 0; k < 7; ++k) wsm[tid * 7 + k] = vals[k] / se;
    }
}

// agg[b,l,c] = sum_k w[b,k] * V[b,(l+sel[k])%L,c]
__global__ __launch_bounds__(256) void aggregate(
    const f16* __restrict__ V, const int* __restrict__ sel,
    const float* __restrict__ wsm, f16* __restrict__ agg)
{
    __shared__ int   sidx[7];
    __shared__ float sw[7];
    const int bl = blockIdx.x;
    const int b = bl >> 11, l = bl & 2047;
    if (threadIdx.x < 7) { sidx[threadIdx.x] = sel[threadIdx.x]; sw[threadIdx.x] = wsm[b * 7 + threadIdx.x]; }
    __syncthreads();
    const int c = threadIdx.x;
    float a0 = 0.f, a1 = 0.f;
#pragma unroll
    for (int k = 0; k < 7; ++k) {
        const int lk = (l + sidx[k]) & 2047;
        const f16* row = V + ((size_t)b * 2048 + lk) * 512;
        a0 += sw[k] * (float)row[c];
        a1 += sw[k] * (float)row[c + 256];
    }
    f16* orow = agg + ((size_t)b * 2048 + l) * 512;
    orow[c]       = (f16)a0;
    orow[c + 256] = (f16)a1;
}

extern "C" void kernel_launch(void* const* d_in, const int* in_sizes, int n_in,
                              void* d_out, int out_size, void* d_ws, size_t ws_size,
                              hipStream_t stream)
{
    (void)in_sizes; (void)n_in; (void)out_size; (void)ws_size;
    const float* queries = (const float*)d_in[0];
    const float* keys    = (const float*)d_in[1];
    const float* values  = (const float*)d_in[2];
    const float* Wq = (const float*)d_in[3];
    const float* bq = (const float*)d_in[4];
    const float* Wk = (const float*)d_in[5];
    const float* bk = (const float*)d_in[6];
    const float* Wv = (const float*)d_in[7];
    const float* bv = (const float*)d_in[8];
    const float* Wo = (const float*)d_in[9];
    const float* bo = (const float*)d_in[10];

    char* p = (char*)d_ws;
    f16*    xh  = (f16*)p;    p += 33554432;   // X f16, reused per projection
    f16*    xl  = (f16*)p;    p += 33554432;   // Sp region, later agg
    f16*    Qt  = (f16*)p;    p += 33554432;   // Q transposed (c, b, t) f16
    f16*    Kt  = (f16*)p;    p += 33554432;   // K transposed f16
    f16*    Vb  = (f16*)p;    p += 33554432;   // V (b, l, c) f16
    f16*    wqh = (f16*)p;    p += 524288;
    f16*    wkh = (f16*)p;    p += 524288;
    f16*    wvh = (f16*)p;    p += 524288;
    f16*    woh = (f16*)p;    p += 524288;
    float*  mv  = (float*)p;  p += 131072;     // mean_value 16 x 2048
    int*    sel = (int*)p;    p += 256;        // top-7 lags
    float*  wsm = (float*)p;  p += 512;        // softmax weights 16 x 7
    float2* Sp  = (float2*)xl;                 // 16 x 64 x 1025 cplx, in xl
    f16*    agg = xl;                          // reuse after Sp consumed

    // weight conversions
    cvt_f16<<<256, 256, 0, stream>>>(Wq, wqh, 65536);
    cvt_f16<<<256, 256, 0, stream>>>(Wk, wkh, 65536);
    cvt_f16<<<256, 256, 0, stream>>>(Wv, wvh, 65536);
    cvt_f16<<<256, 256, 0, stream>>>(Wo, woh, 65536);

    // Q^T = Wq * queries^T, f16 out, stored (c, b*2048+t), +bq
    // M=512 (4 tiles), N=32768 (256 tiles); SWZ=1 groups the 4 M-tiles of a
    // B-panel on one XCD.
    cvt_f16<<<16384, 256, 0, stream>>>(queries, xh, 4194304);
    gemm_nt<1, 2, 8, 1><<<1024, 256, 0, stream>>>(wqh, xh, Qt, 32768, bq, nullptr);
    // K^T
    cvt_f16<<<16384, 256, 0, stream>>>(keys, xh, 4194304);
    gemm_nt<1, 2, 8, 1><<<1024, 256, 0, stream>>>(wkh, xh, Kt, 32768, bk, nullptr);
    // V natural (b,l,c), f16 out, +bv. SWZ=2 groups the 4 N-tiles of an
    // A-panel on one XCD.
    cvt_f16<<<16384, 256, 0, stream>>>(values, xh, 4194304);
    gemm_nt<1, 8, 2, 2><<<1024, 256, 0, stream>>>(xh, wvh, Vb, 512, nullptr, bv);

    // correlation spectra -> mean_value -> selection -> aggregation
    fft_corr<<<dim3(64, 16), 256, 0, stream>>>(Qt, Kt, Sp);
    ifft_mean<<<16, 256, 0, stream>>>(Sp, mv);
    select_topk<<<1, 256, 0, stream>>>(mv, sel, wsm);
    aggregate<<<32768, 256, 0, stream>>>(Vb, sel, wsm, agg);

    // out = agg @ Wo^T + bo  -> d_out f32
    gemm_nt<0, 8, 2, 2><<<1024, 256, 0, stream>>>(agg, woh, (float*)d_out, 512, nullptr, bo);
}